// Round 1
// baseline (2597.182 us; speedup 1.0000x reference)
//
#include <hip/hip_runtime.h>

// ---------------------------------------------------------------------------
// GGNN-obj (N=256, C=151, H=512, T=3). Split-f16 (hi+lo) MFMA on the
// recurrent path, f32 hidden master.
// R10->R11: gate GEMM rewritten as 256x256-tile 8-phase schedule (HK-style):
// 8 waves (2Mx4N, 128x64/wave), BK=64 double-buffered (128KB LDS), raw
// s_barrier + counted vmcnt (stage tile t+1 at phase0 of tile t, drain at
// phase3 -> never a zero-cover drain), XOR-swizzled LDS reads with
// pre-swizzled global source (conflict-free ds_read_b128), setprio(1)
// around each 16-MFMA cluster. Math order unchanged -> bit-identical.
// ---------------------------------------------------------------------------

#define C_     151
#define H_     512
#define NOBJ   256
#define NR     38656      // NOBJ * C_
#define NCH    64         // objects per chunk
#define CH     9664       // NCH * C_
#define CHP    9728       // CH padded to 256-multiple (38 tiles of 256)
#define KPAD   160        // C_ padded to 32-multiple
#define KLDS   168        // LDS row stride for transposed x tiles
#define KA     2560       // A cols in gate GEMM: [av_hi 1024 | av_lo 1024 | h 512]
#define KV     3584       // virtual K: ah*Wh + al*Wh + ah*Wl + h*Wu
#define KB     2560       // physical B cols: [Wh 1024 | Wl 1024 | Wu 512]

typedef _Float16 half8 __attribute__((ext_vector_type(8)));
typedef _Float16 half4 __attribute__((ext_vector_type(4)));
typedef float    f32x4 __attribute__((ext_vector_type(4)));

__device__ __forceinline__ float sigm(float x) { return 1.f / (1.f + expf(-x)); }

__device__ __forceinline__ void gload16(const void* g, void* l) {
    __builtin_amdgcn_global_load_lds(
        (const __attribute__((address_space(1))) void*)g,
        (__attribute__((address_space(3))) void*)l, 16, 0, 0);
}

// Staging swizzle for the 128x32 gemm_kernel path (unchanged):
__device__ __forceinline__ int kqswz(int s) {
    return 8 * (((s & 3) + 8 - ((s >> 2) & 3) - ((s >> 4) & 3)) & 3);
}
__device__ __forceinline__ int fraswz(int lane) {
    const int lb = lane & 15;
    return lb * 32 + 8 * (((lane >> 4) + lb + (lb >> 2)) & 3);
}

__device__ __forceinline__ half8 loadA8(const _Float16* p) { return *(const half8*)p; }
__device__ __forceinline__ half8 loadA8(const float* p) {
    f32x4 a = *(const f32x4*)p;
    f32x4 b = *(const f32x4*)(p + 4);
    half8 o;
    #pragma unroll
    for (int j = 0; j < 4; ++j) { o[j] = (_Float16)a[j]; o[4 + j] = (_Float16)b[j]; }
    return o;
}

// ---------------------------------------------------------------------------
// 128x128-tile GEMM (256 thr, 16x16x32): Out[m,n] = sum_k A[m,k]*B[n,k].
// OP: 0 = f32 store, 1 = f16 store, 2 = relu(v+bias[col]+bias2[...]) -> f16
// ---------------------------------------------------------------------------
template<int OP, typename AT, bool DUPK>
__global__ __launch_bounds__(256, 2)
void gemm_kernel(const AT* __restrict__ A, int lda,
                 const _Float16* __restrict__ B, int ldb,
                 void* __restrict__ Out, int ldo,
                 const float* __restrict__ bias,
                 const float* __restrict__ bias2,
                 int kchunk, int chunkStride)
{
    constexpr bool A16 = (sizeof(AT) == 2);
    __shared__ _Float16 sA[128 * 32];
    __shared__ _Float16 sB[128 * 32];
    const int tid  = threadIdx.x;
    const int lane = tid & 63;
    const int w    = tid >> 6;
    const int m0   = blockIdx.x * 128;
    const int n0   = blockIdx.y * 128;
    const int kbase = blockIdx.z * kchunk;

    const int s0 = tid, s1 = tid + 256;
    const AT* Ap0 = A + (size_t)(m0 + (s0 >> 2)) * lda + kqswz(s0);
    const AT* Ap1 = A + (size_t)(m0 + (s1 >> 2)) * lda + kqswz(s1);
    const _Float16* Bp0 = B + (size_t)(n0 + (s0 >> 2)) * ldb + kbase + kqswz(s0);
    const _Float16* Bp1 = B + (size_t)(n0 + (s1 >> 2)) * ldb + kbase + kqswz(s1);
    const int la0 = 8 * s0;
    const int la1 = 8 * s1;
    _Float16* lA0 = &sA[w * 512];
    _Float16* lA1 = &sA[2048 + w * 512];
    _Float16* lB0 = &sB[w * 512];
    _Float16* lB1 = &sB[2048 + w * 512];

    f32x4 acc[4][4];
    #pragma unroll
    for (int i = 0; i < 4; ++i)
        #pragma unroll
        for (int j = 0; j < 4; ++j)
            #pragma unroll
            for (int r = 0; r < 4; ++r) acc[i][j][r] = 0.f;

    const int mrow = (w >> 1) * 64;
    const int ncol = (w & 1) * 64;
    const int fra  = fraswz(lane);

    for (int k0 = 0; k0 < kchunk; k0 += 32) {
        int kA;
        if (DUPK) kA = (k0 < 2048) ? k0 : ((k0 < 3072) ? k0 - 2048 : k0 - 1024);
        else      kA = kbase + k0;
        if constexpr (A16) {
            __syncthreads();
            gload16(Ap0 + kA, lA0);
            gload16(Ap1 + kA, lA1);
            gload16(Bp0 + k0, lB0);
            gload16(Bp1 + k0, lB1);
            __syncthreads();
        } else {
            half8 va0 = loadA8(Ap0 + kA);
            half8 va1 = loadA8(Ap1 + kA);
            half8 vb0 = *(const half8*)(Bp0 + k0);
            half8 vb1 = *(const half8*)(Bp1 + k0);
            __syncthreads();
            *(half8*)&sA[la0] = va0;
            *(half8*)&sA[la1] = va1;
            *(half8*)&sB[la0] = vb0;
            *(half8*)&sB[la1] = vb1;
            __syncthreads();
        }
        half8 af[4], bf[4];
        #pragma unroll
        for (int i = 0; i < 4; ++i)
            af[i] = *(const half8*)&sA[(mrow + i * 16) * 32 + fra];
        #pragma unroll
        for (int i = 0; i < 4; ++i)
            bf[i] = *(const half8*)&sB[(ncol + i * 16) * 32 + fra];
        #pragma unroll
        for (int mi = 0; mi < 4; ++mi)
            #pragma unroll
            for (int ni = 0; ni < 4; ++ni)
                acc[mi][ni] = __builtin_amdgcn_mfma_f32_16x16x32_f16(af[mi], bf[ni], acc[mi][ni], 0, 0, 0);
    }

    const size_t zoff = (size_t)blockIdx.z * (size_t)chunkStride;
    #pragma unroll
    for (int mi = 0; mi < 4; ++mi) {
        #pragma unroll
        for (int ni = 0; ni < 4; ++ni) {
            #pragma unroll
            for (int r = 0; r < 4; ++r) {
                const int row = m0 + mrow + mi * 16 + (lane >> 4) * 4 + r;
                const int col = n0 + ncol + ni * 16 + (lane & 15);
                float v = acc[mi][ni][r];
                const size_t o = zoff + (size_t)row * ldo + col;
                if (OP == 0) {
                    ((float*)Out)[o] = v;
                } else if (OP == 1) {
                    ((_Float16*)Out)[o] = (_Float16)v;
                } else {
                    const unsigned n = (unsigned)row / 151u;
                    v += bias[col] + bias2[n * 512u + col];
                    v = v > 0.f ? v : 0.f;
                    ((_Float16*)Out)[o] = (_Float16)v;
                }
            }
        }
    }
}

// ---------------------------------------------------------------------------
// 256x256-tile 8-phase gate GEMM. 512 thr = 8 waves (2M x 4N), per-wave
// 128x64 output, BK=64, double-buffered (2 x 64KB LDS). Per K-tile: 4 phases,
// each = {ds_read frag subtile || stage || barrier || lgkmcnt(0) || setprio(1)
// 16 MFMA setprio(0) || barrier}. Stage of tile t+1 issued at phase 0 of
// tile t; single vmcnt(0) at phase 3 (loads then ~3 phases old). LDS 16B
// group g at row r holds logical k-group g^(r&7): pre-swizzled global source
// keeps global_load_lds linear; reads XOR back -> lanes 0..7 cover all 32
// banks (conflict-free ds_read_b128).
// Virtual K remap (DUPK): A [ah|al|ah|h], B [Wh|Wh|Wl|Wu]; 64-tiles never
// straddle the 1024-aligned segment boundaries.
// ---------------------------------------------------------------------------
__global__ __launch_bounds__(512, 2)
void gemm256(const _Float16* __restrict__ A, const _Float16* __restrict__ B,
             _Float16* __restrict__ Out)
{
    constexpr int LDA = KA;       // 2560
    constexpr int LDB = KB;       // 2560
    constexpr int LDO = 1536;
    constexpr int NT  = KV / 64;  // 56 K-tiles
    __shared__ _Float16 lds[2][32768];   // [buf][ A 256x64 | B 256x64 ]  128 KB

    const int tid  = threadIdx.x;
    const int lane = tid & 63;
    const int w    = tid >> 6;               // 0..7
    const int m0   = blockIdx.x * 256;
    const int n0   = blockIdx.y * 256;

    // ---- staging geometry: thread covers rows tr+{0,64,128,192}, 16B grp ----
    const int tr  = tid >> 3;                        // 0..63
    const int swz = ((tid & 7) ^ (tr & 7)) << 3;     // pre-swizzled col (f16)
    const _Float16* Ap = A + (size_t)(m0 + tr) * LDA + swz;
    const _Float16* Bp = B + (size_t)(n0 + tr) * LDB + swz;
    const int ldsbase = w << 9;                      // wave slot (f16) per round

    auto stage = [&](int buf, int kAb, int kBb) {
        _Float16* L = &lds[buf][0];
        #pragma unroll
        for (int h = 0; h < 2; ++h) {
            #pragma unroll
            for (int r = 0; r < 2; ++r) {
                const int ro = h * 128 + r * 64;
                gload16(Ap + (size_t)ro * LDA + kAb, L + h * 8192 + r * 4096 + ldsbase);
                gload16(Bp + (size_t)ro * LDB + kBb, L + 16384 + h * 8192 + r * 4096 + ldsbase);
            }
        }
    };

    // ---- fragment read (XOR-unswizzle) ----
    const int lb = lane & 15;
    const int lq = lane >> 4;
    auto frag = [&](const _Float16* base, int row0, int ks) -> half8 {
        const int row = row0 + lb;                   // row0 multiple of 16
        const int kg  = ks * 4 + lq;                 // logical 8-f16 k-group
        return *(const half8*)&base[row * 64 + ((kg ^ (row & 7)) << 3)];
    };

    const int wm = (w >> 2) * 128;                   // wave M offset in tile
    const int wn = (w & 3) * 64;                     // wave N offset in tile

    f32x4 acc[8][4];
    #pragma unroll
    for (int i = 0; i < 8; ++i)
        #pragma unroll
        for (int j = 0; j < 4; ++j)
            #pragma unroll
            for (int r = 0; r < 4; ++r) acc[i][j][r] = 0.f;

    half8 a[4][2], b0[2][2], b1[2][2];

#define QUAD(MQ, NQ, BB) do {                                                   \
    __builtin_amdgcn_s_barrier();                                               \
    asm volatile("s_waitcnt lgkmcnt(0)" ::: "memory");                          \
    __builtin_amdgcn_s_setprio(1);                                              \
    _Pragma("unroll")                                                           \
    for (int i = 0; i < 4; ++i) {                                               \
        _Pragma("unroll")                                                       \
        for (int j = 0; j < 2; ++j) {                                           \
            _Pragma("unroll")                                                   \
            for (int ks = 0; ks < 2; ++ks)                                      \
                acc[(MQ) * 4 + i][(NQ) * 2 + j] =                               \
                    __builtin_amdgcn_mfma_f32_16x16x32_f16(                     \
                        a[i][ks], BB[j][ks],                                    \
                        acc[(MQ) * 4 + i][(NQ) * 2 + j], 0, 0, 0);              \
        }                                                                       \
    }                                                                           \
    __builtin_amdgcn_s_setprio(0);                                              \
    __builtin_amdgcn_s_barrier();                                               \
} while (0)

    // ---- prologue: stage tile 0 -> buf 0 ----
    stage(0, 0, 0);
    asm volatile("s_waitcnt vmcnt(0)" ::: "memory");
    __builtin_amdgcn_s_barrier();

    for (int t = 0; t < NT; ++t) {
        const _Float16* sA = &lds[t & 1][0];
        const _Float16* sB = &lds[t & 1][16384];

        // phase 0: read A(m-half0) + B(n-half0); stage tile t+1; MFMA (0,0)
        #pragma unroll
        for (int i = 0; i < 4; ++i) {
            a[i][0] = frag(sA, wm + i * 16, 0);
            a[i][1] = frag(sA, wm + i * 16, 1);
        }
        #pragma unroll
        for (int j = 0; j < 2; ++j) {
            b0[j][0] = frag(sB, wn + j * 16, 0);
            b0[j][1] = frag(sB, wn + j * 16, 1);
        }
        if (t + 1 < NT) {
            const int kk  = (t + 1) * 64;
            const int kAb = (kk < 2048) ? kk : ((kk < 3072) ? kk - 2048 : kk - 1024);
            const int kBb = (kk < 1024) ? kk : kk - 1024;
            stage((t + 1) & 1, kAb, kBb);
        }
        QUAD(0, 0, b0);

        // phase 1: read B(n-half1); MFMA (0,1)
        #pragma unroll
        for (int j = 0; j < 2; ++j) {
            b1[j][0] = frag(sB, wn + 32 + j * 16, 0);
            b1[j][1] = frag(sB, wn + 32 + j * 16, 1);
        }
        QUAD(0, 1, b1);

        // phase 2: read A(m-half1); MFMA (1,1)
        #pragma unroll
        for (int i = 0; i < 4; ++i) {
            a[i][0] = frag(sA, wm + 64 + i * 16, 0);
            a[i][1] = frag(sA, wm + 64 + i * 16, 1);
        }
        QUAD(1, 1, b1);

        // phase 3: no reads; publish next tile's stages; MFMA (1,0)
        asm volatile("s_waitcnt vmcnt(0)" ::: "memory");
        QUAD(1, 0, b0);
    }
#undef QUAD

    #pragma unroll
    for (int mi = 0; mi < 8; ++mi) {
        #pragma unroll
        for (int ni = 0; ni < 4; ++ni) {
            #pragma unroll
            for (int r = 0; r < 4; ++r) {
                const int row = m0 + wm + mi * 16 + (lane >> 4) * 4 + r;
                const int col = n0 + wn + ni * 16 + (lane & 15);
                Out[(size_t)row * LDO + col] = (_Float16)acc[mi][ni][r];
            }
        }
    }
}

// ---------------------------------------------------------------------------
// Mix kernel (one 64-object chunk), split precision, xcast fused.
// ---------------------------------------------------------------------------
__global__ __launch_bounds__(256, 2)
void mix_kernel(const float* __restrict__ hid, const float* __restrict__ S,
                const _Float16* __restrict__ MTh, const _Float16* __restrict__ MTl,
                const _Float16* __restrict__ Mrh, const _Float16* __restrict__ Mrl,
                _Float16* __restrict__ AVH, int cbase)
{
    __shared__ _Float16 sxh[64 * KLDS];
    __shared__ _Float16 sxl[64 * KLDS];
    const int n  = blockIdx.x;
    const int h0 = blockIdx.y * 64;
    const int tid = threadIdx.x;

    #pragma unroll
    for (int i = 0; i < 5; ++i) {
        const int s  = tid + 256 * i;          // 0..1279
        const int c  = s >> 3;                 // 0..159
        const int hg = s & 7;
        half8 oh, ol;
        if (c < C_) {
            const float* hp = &hid[(size_t)(cbase + n * C_ + c) * H_ + h0 + hg * 8];
            const float* sp = &S[c * H_ + h0 + hg * 8];
            half8 hh;
            #pragma unroll
            for (int j = 0; j < 8; ++j) {
                const float hv = hp[j];
                const float x = sp[j] - hv;
                const _Float16 hi = (_Float16)x;
                oh[j] = hi;
                ol[j] = (_Float16)(x - (float)hi);
                hh[j] = (_Float16)hv;
            }
            *(half8*)&AVH[(size_t)(n * C_ + c) * KA + 2048 + h0 + hg * 8] = hh;
        } else {
            #pragma unroll
            for (int j = 0; j < 8; ++j) { oh[j] = (_Float16)0.f; ol[j] = (_Float16)0.f; }
        }
        #pragma unroll
        for (int j = 0; j < 8; ++j) {
            sxh[(hg * 8 + j) * KLDS + c] = oh[j];
            sxl[(hg * 8 + j) * KLDS + c] = ol[j];
        }
    }
    __syncthreads();

    const int lane = tid & 63;
    const int w    = tid >> 6;
    const _Float16* Mhi = (w >> 1) ? Mrh : MTh;
    const _Float16* Mlo = (w >> 1) ? Mrl : MTl;
    const int hb = (w & 1) * 32;

    f32x4 acc[10][2];
    #pragma unroll
    for (int i = 0; i < 10; ++i)
        #pragma unroll
        for (int j = 0; j < 2; ++j)
            #pragma unroll
            for (int r = 0; r < 4; ++r) acc[i][j][r] = 0.f;

    #pragma unroll
    for (int pass = 0; pass < 3; ++pass) {
        const _Float16* Ma = (pass == 2) ? Mlo : Mhi;
        const _Float16* X  = (pass == 1) ? sxl : sxh;
        #pragma unroll
        for (int kk = 0; kk < 5; ++kk) {
            const int k0 = kk * 32;
            half8 bf[2];
            #pragma unroll
            for (int ht = 0; ht < 2; ++ht)
                bf[ht] = *(const half8*)&X[(hb + ht * 16 + (lane & 15)) * KLDS + k0 + 8 * (lane >> 4)];
            #pragma unroll
            for (int dt = 0; dt < 10; ++dt) {
                half8 af = *(const half8*)&Ma[(dt * 16 + (lane & 15)) * KPAD + k0 + 8 * (lane >> 4)];
                acc[dt][0] = __builtin_amdgcn_mfma_f32_16x16x32_f16(af, bf[0], acc[dt][0], 0, 0, 0);
                acc[dt][1] = __builtin_amdgcn_mfma_f32_16x16x32_f16(af, bf[1], acc[dt][1], 0, 0, 0);
            }
        }
    }

    const int mixoff = (w >> 1) * 512;
    #pragma unroll
    for (int dt = 0; dt < 10; ++dt) {
        #pragma unroll
        for (int ht = 0; ht < 2; ++ht) {
            #pragma unroll
            for (int r = 0; r < 4; ++r) {
                const int d = dt * 16 + (lane >> 4) * 4 + r;
                if (d < C_) {
                    const int h = h0 + hb + ht * 16 + (lane & 15);
                    const float v = acc[dt][ht][r];
                    const _Float16 hi = (_Float16)v;
                    const _Float16 lo = (_Float16)(v - (float)hi);
                    _Float16* rowp = AVH + (size_t)(n * C_ + d) * KA + mixoff + h;
                    rowp[0]    = hi;
                    rowp[1024] = lo;
                }
            }
        }
    }
}

// --------------------------- small kernels ---------------------------------

__global__ void k_sreduce(const float* __restrict__ hid, float* __restrict__ Stmp)
{
    const int c  = blockIdx.x;      // 151
    const int g  = blockIdx.y;      // 8
    const int hw = threadIdx.x;     // 64
    const float* p = hid + (size_t)c * H_ + hw * 8;
    float s[8];
    #pragma unroll
    for (int j = 0; j < 8; ++j) s[j] = 0.f;
    const size_t stride = (size_t)C_ * H_;
    for (int n = g * 32; n < g * 32 + 32; ++n) {
        f32x4 a = *(const f32x4*)(p + (size_t)n * stride);
        f32x4 b = *(const f32x4*)(p + (size_t)n * stride + 4);
        #pragma unroll
        for (int j = 0; j < 4; ++j) { s[j] += a[j]; s[4 + j] += b[j]; }
    }
    float* o = Stmp + (size_t)g * (C_ * H_) + c * H_ + hw * 8;
    *(f32x4*)o       = f32x4{s[0], s[1], s[2], s[3]};
    *(f32x4*)(o + 4) = f32x4{s[4], s[5], s[6], s[7]};
}

__global__ void k_sfold(const float* __restrict__ Stmp, float* __restrict__ S)
{
    const int idx = blockIdx.x * 256 + threadIdx.x;   // 77312
    float s = 0.f;
    #pragma unroll
    for (int g = 0; g < 8; ++g) s += Stmp[(size_t)g * (C_ * H_) + idx];
    S[idx] = s;
}

__global__ void k_ew1(_Float16* __restrict__ pre, const float* __restrict__ hid,
                      const float* __restrict__ bz, const float* __restrict__ br, int cbase)
{
    const int idx = blockIdx.x * 256 + threadIdx.x;   // CH*128
    const unsigned r = idx >> 7;
    const int o4 = (idx & 127) << 2;
    const size_t base = (size_t)r * 1536;
    half4 zp = *(const half4*)&pre[base + o4];
    half4 rp = *(const half4*)&pre[base + 512 + o4];
    f32x4 hd = *(const f32x4*)&hid[(size_t)(cbase + r) * H_ + o4];
    f32x4 bz4 = *(const f32x4*)&bz[o4];
    f32x4 br4 = *(const f32x4*)&br[o4];
    half4 zs, rh;
    #pragma unroll
    for (int j = 0; j < 4; ++j) {
        float z = sigm((float)zp[j] + bz4[j]);
        float rr = sigm((float)rp[j] + br4[j]);
        zs[j] = (_Float16)z;
        rh[j] = (_Float16)(rr * hd[j]);
    }
    *(half4*)&pre[base + o4] = zs;
    *(half4*)&pre[base + 512 + o4] = rh;
}

// EW2: hv = tanh(pre_w5 + p5a + p5b + b5); h = (1-z)h + z*hv -> hid (f32)
__global__ void k_ew2(const _Float16* __restrict__ pre, const _Float16* __restrict__ p5a,
                      const _Float16* __restrict__ p5b,
                      float* __restrict__ hid, const float* __restrict__ b5, int cbase)
{
    const int idx = blockIdx.x * 256 + threadIdx.x;   // CH*128
    const unsigned r = idx >> 7;
    const int o4 = (idx & 127) << 2;
    const size_t base = (size_t)r * 1536;
    half4 w5 = *(const half4*)&pre[base + 1024 + o4];
    half4 pa = *(const half4*)&p5a[(size_t)r * H_ + o4];
    half4 pb = *(const half4*)&p5b[(size_t)r * H_ + o4];
    half4 zz = *(const half4*)&pre[base + o4];
    f32x4 hd = *(const f32x4*)&hid[(size_t)(cbase + r) * H_ + o4];
    f32x4 b54 = *(const f32x4*)&b5[o4];
    #pragma unroll
    for (int j = 0; j < 4; ++j) {
        float t = tanhf((float)w5[j] + (float)pa[j] + (float)pb[j] + b54[j]);
        float z = (float)zz[j];
        hd[j] = (1.f - z) * hd[j] + z * t;
    }
    *(f32x4*)&hid[(size_t)(cbase + r) * H_ + o4] = hd;
}

// --------------------------- prep kernels ----------------------------------

// Wbig [1536, 2560]: row op=(g*512+o): [0,1024)=Wg_hi; [1024,2048)=Wg_lo;
// [2048,2560)=Ug (0 for g=2).
__global__ void prep_wbig(const float* w3w, const float* w3u,
                          const float* w4w, const float* w4u,
                          const float* w5w, const float* w5u,
                          _Float16* __restrict__ Wbig)
{
    const int idx = blockIdx.x * 256 + threadIdx.x;   // 1536*2560
    const int op = idx / KB;
    const int j = idx - op * KB;
    const int g = op >> 9, o = op & 511;
    const float* ww = (g == 0) ? w3w : (g == 1) ? w4w : w5w;
    const float* wu = (g == 0) ? w3u : (g == 1) ? w4u : w5u;
    _Float16 out;
    if (j < 1024) {
        out = (_Float16)ww[o * 1024 + j];
    } else if (j < 2048) {
        const float v = ww[o * 1024 + (j - 1024)];
        const _Float16 hi = (_Float16)v;
        out = (_Float16)(v - (float)hi);
    } else {
        out = (g < 2) ? (_Float16)wu[o * 512 + (j - 2048)] : (_Float16)0.f;
    }
    Wbig[idx] = out;
}

__global__ void prep_m(const float* __restrict__ matrix,
                       _Float16* __restrict__ MTh, _Float16* __restrict__ MTl,
                       _Float16* __restrict__ Mrh, _Float16* __restrict__ Mrl)
{
    const int idx = blockIdx.x * 256 + threadIdx.x;   // KPAD*KPAD
    const int d = idx / KPAD, c = idx - d * KPAD;
    float vT = 0.f, vR = 0.f;
    if (d < C_ && c < C_) { vT = matrix[c * C_ + d]; vR = matrix[d * C_ + c]; }
    const _Float16 th = (_Float16)vT;
    const _Float16 rh = (_Float16)vR;
    MTh[idx] = th; MTl[idx] = (_Float16)(vT - (float)th);
    Mrh[idx] = rh; Mrl[idx] = (_Float16)(vR - (float)rh);
}

__global__ void prep_wout(const float* __restrict__ wout,
                          _Float16* __restrict__ WL, _Float16* __restrict__ WR)
{
    const int idx = blockIdx.x * 256 + threadIdx.x;   // 512*512
    const int o = idx >> 9, j = idx & 511;
    WL[idx] = (_Float16)wout[o * 1024 + j];
    WR[idx] = (_Float16)wout[o * 1024 + 512 + j];
}

// only the 151 real rows; rows 151..255 stay poisoned (never read downstream)
__global__ void prep_wcls(const float* __restrict__ wcls, _Float16* __restrict__ w16)
{
    const int k = blockIdx.x * 256 + threadIdx.x;   // 77312
    const int d = blockIdx.y;                        // 0..150
    w16[(size_t)d * (C_ * H_) + k] = (_Float16)wcls[(size_t)d * (C_ * H_) + k];
}

__global__ void k_cast(const float* __restrict__ src, _Float16* __restrict__ dst, int n)
{
    const int i = blockIdx.x * 256 + threadIdx.x;
    if (i < n) dst[i] = (_Float16)src[i];
}

__global__ void prep_bias(const float* b3w, const float* b3u, const float* b4w,
                          const float* b4u, const float* b5w, const float* b5u,
                          float* bz, float* br, float* b5)
{
    const int i = threadIdx.x;   // 512 threads
    bz[i] = b3w[i] + b3u[i];
    br[i] = b4w[i] + b4u[i];
    b5[i] = b5w[i] + b5u[i];
}

__global__ void prep_hid(const float* __restrict__ input, float* __restrict__ hid)
{
    const int idx = blockIdx.x * 256 + threadIdx.x;   // NR*128
    const unsigned row = idx >> 7;
    const int h4 = (idx & 127) << 2;
    const unsigned n = row / 151u;
    f32x4 v = *(const f32x4*)&input[(size_t)n * H_ + h4];
    *(f32x4*)&hid[(size_t)row * H_ + h4] = v;
}

__global__ void k_reduce(const float* __restrict__ partial, const float* __restrict__ bcls,
                         float* __restrict__ out)
{
    const int idx = blockIdx.x * 256 + threadIdx.x;   // NR
    const unsigned n = (unsigned)idx / 151u;
    const unsigned d = (unsigned)idx - n * 151u;
    float s = 0.f;
    for (int z = 0; z < C_; ++z)
        s += partial[(size_t)z * (NOBJ * 256) + n * 256 + d];
    out[idx] = s + bcls[d];
}

// ---------------------------------------------------------------------------

extern "C" void kernel_launch(void* const* d_in, const int* in_sizes, int n_in,
                              void* d_out, int out_size, void* d_ws, size_t ws_size,
                              hipStream_t stream)
{
    const float* input  = (const float*)d_in[0];
    const float* matrix = (const float*)d_in[1];
    const float* w3w = (const float*)d_in[2];
    const float* b3w = (const float*)d_in[3];
    const float* w3u = (const float*)d_in[4];
    const float* b3u = (const float*)d_in[5];
    const float* w4w = (const float*)d_in[6];
    const float* b4w = (const float*)d_in[7];
    const float* w4u = (const float*)d_in[8];
    const float* b4u = (const float*)d_in[9];
    const float* w5w = (const float*)d_in[10];
    const float* b5w = (const float*)d_in[11];
    const float* w5u = (const float*)d_in[12];
    const float* b5u = (const float*)d_in[13];
    const float* wout = (const float*)d_in[14];
    const float* bout = (const float*)d_in[15];
    const float* wcls = (const float*)d_in[16];
    const float* bcls = (const float*)d_in[17];
    float* obj = (float*)d_out;

    char* ws = (char*)d_ws;
    size_t off = 0;
    auto take = [&](size_t bytes) -> char* {
        off = (off + 255) & ~(size_t)255;
        char* p = ws + off;
        off += bytes;
        return p;
    };

    _Float16* Wbig  = (_Float16*)take((size_t)1536 * KB * 2);     //  7.86 MB
    _Float16* MTh   = (_Float16*)take((size_t)KPAD * KPAD * 2);
    _Float16* MTl   = (_Float16*)take((size_t)KPAD * KPAD * 2);
    _Float16* Mrh   = (_Float16*)take((size_t)KPAD * KPAD * 2);
    _Float16* Mrl   = (_Float16*)take((size_t)KPAD * KPAD * 2);
    _Float16* W5u16 = (_Float16*)take((size_t)512 * 512 * 2);
    _Float16* WL16  = (_Float16*)take((size_t)512 * 512 * 2);
    _Float16* WR16  = (_Float16*)take((size_t)512 * 512 * 2);
    _Float16* in16  = (_Float16*)take((size_t)256 * 512 * 2);
    float*    bz    = (float*)take(512 * 4);
    float*    br    = (float*)take(512 * 4);
    float*    b5    = (float*)take(512 * 4);
    float*    Stmp  = (float*)take((size_t)8 * C_ * H_ * 4);      //  2.47 MB
    float*    S32   = (float*)take((size_t)C_ * H_ * 4);
    float*    base  = (float*)take((size_t)256 * 512 * 4);
    float*    hid32 = (float*)take((size_t)NR * H_ * 4);          // 79.17 MB
    _Float16* AVH   = (_Float16*)take((size_t)CHP * KA * 2);      // 49.81 MB
    _Float16* prec  = (_Float16*)take((size_t)CHP * 1536 * 2);    // 29.88 MB
    // time-based aliases:
    _Float16* p5u = AVH;                 // 2 split-K halves: 2*CHP*512*2 = 19.9 MB < AVH
    _Float16* OUT16 = AVH;               // epilogue out (after loop)
    _Float16* Wcls16 = (_Float16*)hid32; // hid dead after epilogue GEMM
    float* partial = (float*)((char*)hid32 + (size_t)NOBJ * C_ * H_ * 2);

    (void)in_sizes; (void)n_in; (void)out_size; (void)ws_size;

    // ---- prep ----
    prep_wbig<<<dim3((1536 * KB) / 256), 256, 0, stream>>>(w3w, w3u, w4w, w4u, w5w, w5u, Wbig);
    prep_m<<<dim3((KPAD * KPAD) / 256), 256, 0, stream>>>(matrix, MTh, MTl, Mrh, Mrl);
    k_cast<<<dim3((512 * 512) / 256), 256, 0, stream>>>(w5u, W5u16, 512 * 512);
    prep_wout<<<dim3((512 * 512) / 256), 256, 0, stream>>>(wout, WL16, WR16);
    k_cast<<<dim3((256 * 512) / 256), 256, 0, stream>>>(input, in16, 256 * 512);
    prep_bias<<<dim3(1), 512, 0, stream>>>(b3w, b3u, b4w, b4u, b5w, b5u, bz, br, b5);
    prep_hid<<<dim3((NR * 128) / 256), 256, 0, stream>>>(input, hid32);
    gemm_kernel<0, _Float16, false><<<dim3(2, 4, 1), 256, 0, stream>>>(
        in16, 512, WR16, 512, base, 512, nullptr, nullptr, 512, 0);

    // ---- 3 GGNN steps, 4 object-chunks each ----
    for (int t = 0; t < 3; ++t) {
        k_sreduce<<<dim3(C_, 8), 64, 0, stream>>>(hid32, Stmp);
        k_sfold<<<dim3((C_ * H_) / 256), 256, 0, stream>>>(Stmp, S32);
        for (int cc = 0; cc < 4; ++cc) {
            const int cbase = cc * CH;
            mix_kernel<<<dim3(NCH, 8), 256, 0, stream>>>(
                hid32, S32, MTh, MTl, Mrh, Mrl, AVH, cbase);
            // gate GEMM (virtual K=3584 over physical B 2560), 256x256 8-phase
            gemm256<<<dim3(CHP / 256, 1536 / 256, 1), 512, 0, stream>>>(
                AVH, Wbig, prec);
            k_ew1<<<dim3((CH * 128) / 256), 256, 0, stream>>>(prec, hid32, bz, br, cbase);
            // p5u = (r*h) @ W5u^T, split-K=2 (f16 partials summed in ew2)
            gemm_kernel<1, _Float16, false><<<dim3(CHP / 128, 4, 2), 256, 0, stream>>>(
                prec + 512, 1536, W5u16, 512, p5u, 512, nullptr, nullptr, 256, CHP * 512);
            k_ew2<<<dim3((CH * 128) / 256), 256, 0, stream>>>(
                prec, p5u, p5u + (size_t)CHP * 512, hid32, b5, cbase);
        }
    }

    // ---- epilogue: OUT = relu(hid @ WL^T + base[n] + bout)  (A is f32) ----
    gemm_kernel<2, float, false><<<dim3(NR / 128, 512 / 128, 1), 256, 0, stream>>>(
        hid32, 512, WL16, 512, OUT16, 512, bout, base, 512, 0);

    // ---- classifier: split-K over 151 chunks of 512 ----
    prep_wcls<<<dim3((C_ * H_) / 256, C_), 256, 0, stream>>>(wcls, Wcls16);
    gemm_kernel<0, _Float16, false><<<dim3(NOBJ / 128, 256 / 128, C_), 256, 0, stream>>>(
        OUT16, C_ * H_, Wcls16, C_ * H_, partial, 256, nullptr, nullptr, 512, NOBJ * 256);
    k_reduce<<<dim3(NR / 256), 256, 0, stream>>>(partial, bcls, obj);
}

// Round 2
// 2542.131 us; speedup vs baseline: 1.0217x; 1.0217x over previous
//
#include <hip/hip_runtime.h>

// ---------------------------------------------------------------------------
// GGNN-obj (N=256, C=151, H=512, T=3). Split-f16 (hi+lo) MFMA on the
// recurrent path, f32 hidden master.
// R11->R12: gate GEMM phases software-pipelined: ds_reads issued in phase p
// feed phase p+1's MFMA, so LDS pipe overlaps MFMA pipe (R11 serialized them:
// 5030 cyc/tile = 2060 MFMA + 1714 LDS + overhead). One barrier per phase
// (4/tile), lgkmcnt(0) before each barrier (cross-wave WAR on staged buffer),
// sched_barrier(0) after (pin MFMAs, rule 18), vmcnt(0) only at P2.
// Quadrant order (aL*bA, aL*bB, aH*bA, aH*bB) chosen so next-tile frag reads
// (aL at P2, bA at P3) never clobber a live register. Bijective XCD swizzle
// (A-panel-major) for L2-local staging. Math order unchanged -> bit-identical.
// ---------------------------------------------------------------------------

#define C_     151
#define H_     512
#define NOBJ   256
#define NR     38656      // NOBJ * C_
#define NCH    64         // objects per chunk
#define CH     9664       // NCH * C_
#define CHP    9728       // CH padded to 256-multiple (38 tiles of 256)
#define KPAD   160        // C_ padded to 32-multiple
#define KLDS   168        // LDS row stride for transposed x tiles
#define KA     2560       // A cols in gate GEMM: [av_hi 1024 | av_lo 1024 | h 512]
#define KV     3584       // virtual K: ah*Wh + al*Wh + ah*Wl + h*Wu
#define KB     2560       // physical B cols: [Wh 1024 | Wl 1024 | Wu 512]

typedef _Float16 half8 __attribute__((ext_vector_type(8)));
typedef _Float16 half4 __attribute__((ext_vector_type(4)));
typedef float    f32x4 __attribute__((ext_vector_type(4)));

__device__ __forceinline__ float sigm(float x) { return 1.f / (1.f + expf(-x)); }

__device__ __forceinline__ void gload16(const void* g, void* l) {
    __builtin_amdgcn_global_load_lds(
        (const __attribute__((address_space(1))) void*)g,
        (__attribute__((address_space(3))) void*)l, 16, 0, 0);
}

// Staging swizzle for the 128x32 gemm_kernel path (unchanged):
__device__ __forceinline__ int kqswz(int s) {
    return 8 * (((s & 3) + 8 - ((s >> 2) & 3) - ((s >> 4) & 3)) & 3);
}
__device__ __forceinline__ int fraswz(int lane) {
    const int lb = lane & 15;
    return lb * 32 + 8 * (((lane >> 4) + lb + (lb >> 2)) & 3);
}

__device__ __forceinline__ half8 loadA8(const _Float16* p) { return *(const half8*)p; }
__device__ __forceinline__ half8 loadA8(const float* p) {
    f32x4 a = *(const f32x4*)p;
    f32x4 b = *(const f32x4*)(p + 4);
    half8 o;
    #pragma unroll
    for (int j = 0; j < 4; ++j) { o[j] = (_Float16)a[j]; o[4 + j] = (_Float16)b[j]; }
    return o;
}

// ---------------------------------------------------------------------------
// 128x128-tile GEMM (256 thr, 16x16x32): Out[m,n] = sum_k A[m,k]*B[n,k].
// OP: 0 = f32 store, 1 = f16 store, 2 = relu(v+bias[col]+bias2[...]) -> f16
// ---------------------------------------------------------------------------
template<int OP, typename AT, bool DUPK>
__global__ __launch_bounds__(256, 2)
void gemm_kernel(const AT* __restrict__ A, int lda,
                 const _Float16* __restrict__ B, int ldb,
                 void* __restrict__ Out, int ldo,
                 const float* __restrict__ bias,
                 const float* __restrict__ bias2,
                 int kchunk, int chunkStride)
{
    constexpr bool A16 = (sizeof(AT) == 2);
    __shared__ _Float16 sA[128 * 32];
    __shared__ _Float16 sB[128 * 32];
    const int tid  = threadIdx.x;
    const int lane = tid & 63;
    const int w    = tid >> 6;
    const int m0   = blockIdx.x * 128;
    const int n0   = blockIdx.y * 128;
    const int kbase = blockIdx.z * kchunk;

    const int s0 = tid, s1 = tid + 256;
    const AT* Ap0 = A + (size_t)(m0 + (s0 >> 2)) * lda + kqswz(s0);
    const AT* Ap1 = A + (size_t)(m0 + (s1 >> 2)) * lda + kqswz(s1);
    const _Float16* Bp0 = B + (size_t)(n0 + (s0 >> 2)) * ldb + kbase + kqswz(s0);
    const _Float16* Bp1 = B + (size_t)(n0 + (s1 >> 2)) * ldb + kbase + kqswz(s1);
    const int la0 = 8 * s0;
    const int la1 = 8 * s1;
    _Float16* lA0 = &sA[w * 512];
    _Float16* lA1 = &sA[2048 + w * 512];
    _Float16* lB0 = &sB[w * 512];
    _Float16* lB1 = &sB[2048 + w * 512];

    f32x4 acc[4][4];
    #pragma unroll
    for (int i = 0; i < 4; ++i)
        #pragma unroll
        for (int j = 0; j < 4; ++j)
            #pragma unroll
            for (int r = 0; r < 4; ++r) acc[i][j][r] = 0.f;

    const int mrow = (w >> 1) * 64;
    const int ncol = (w & 1) * 64;
    const int fra  = fraswz(lane);

    for (int k0 = 0; k0 < kchunk; k0 += 32) {
        int kA;
        if (DUPK) kA = (k0 < 2048) ? k0 : ((k0 < 3072) ? k0 - 2048 : k0 - 1024);
        else      kA = kbase + k0;
        if constexpr (A16) {
            __syncthreads();
            gload16(Ap0 + kA, lA0);
            gload16(Ap1 + kA, lA1);
            gload16(Bp0 + k0, lB0);
            gload16(Bp1 + k0, lB1);
            __syncthreads();
        } else {
            half8 va0 = loadA8(Ap0 + kA);
            half8 va1 = loadA8(Ap1 + kA);
            half8 vb0 = *(const half8*)(Bp0 + k0);
            half8 vb1 = *(const half8*)(Bp1 + k0);
            __syncthreads();
            *(half8*)&sA[la0] = va0;
            *(half8*)&sA[la1] = va1;
            *(half8*)&sB[la0] = vb0;
            *(half8*)&sB[la1] = vb1;
            __syncthreads();
        }
        half8 af[4], bf[4];
        #pragma unroll
        for (int i = 0; i < 4; ++i)
            af[i] = *(const half8*)&sA[(mrow + i * 16) * 32 + fra];
        #pragma unroll
        for (int i = 0; i < 4; ++i)
            bf[i] = *(const half8*)&sB[(ncol + i * 16) * 32 + fra];
        #pragma unroll
        for (int mi = 0; mi < 4; ++mi)
            #pragma unroll
            for (int ni = 0; ni < 4; ++ni)
                acc[mi][ni] = __builtin_amdgcn_mfma_f32_16x16x32_f16(af[mi], bf[ni], acc[mi][ni], 0, 0, 0);
    }

    const size_t zoff = (size_t)blockIdx.z * (size_t)chunkStride;
    #pragma unroll
    for (int mi = 0; mi < 4; ++mi) {
        #pragma unroll
        for (int ni = 0; ni < 4; ++ni) {
            #pragma unroll
            for (int r = 0; r < 4; ++r) {
                const int row = m0 + mrow + mi * 16 + (lane >> 4) * 4 + r;
                const int col = n0 + ncol + ni * 16 + (lane & 15);
                float v = acc[mi][ni][r];
                const size_t o = zoff + (size_t)row * ldo + col;
                if (OP == 0) {
                    ((float*)Out)[o] = v;
                } else if (OP == 1) {
                    ((_Float16*)Out)[o] = (_Float16)v;
                } else {
                    const unsigned n = (unsigned)row / 151u;
                    v += bias[col] + bias2[n * 512u + col];
                    v = v > 0.f ? v : 0.f;
                    ((_Float16*)Out)[o] = (_Float16)v;
                }
            }
        }
    }
}

// ---------------------------------------------------------------------------
// 256x256-tile gate GEMM, software-pipelined 4-phase schedule.
// 512 thr = 8 waves (2M x 4N), per-wave 128x64 output, BK=64, double-buffered
// LDS (128 KB). Phase p issues the ds_reads consumed by phase p+1, so the
// LDS reads overlap the MFMA burst. Per phase: {lgkmcnt(0); [vmcnt(0) @P2];
// s_barrier; sched_barrier(0); [stage @P0]; ds_reads(next); setprio(1);
// 16 MFMA; setprio(0)}. Frag lifetimes: aL read@P2(next buf) used P0,P1;
// aH read@P1 used P2,P3; bA read@P3(next) used P0,P2; bB read@P0 used P1,P3.
// Quadrants: P0=aL*bA(q00) P1=aL*bB(q01) P2=aH*bA(q10) P3=aH*bB(q11).
// XOR-swizzled LDS (pre-swizzled global source) -> conflict-free ds_read_b128.
// Bijective XCD swizzle, A-panel-major: co-resident blocks on an XCD share
// B (7.9MB) and neighboring A panels -> L2-hit staging.
// ---------------------------------------------------------------------------
__global__ __launch_bounds__(512, 2)
void gemm256(const _Float16* __restrict__ A, const _Float16* __restrict__ B,
             _Float16* __restrict__ Out)
{
    constexpr int LDA = KA;       // 2560
    constexpr int LDB = KB;       // 2560
    constexpr int LDO = 1536;
    constexpr int NT  = KV / 64;  // 56 K-tiles
    __shared__ _Float16 lds[2][32768];   // [buf][ A 256x64 | B 256x64 ]  128 KB

    const int tid  = threadIdx.x;
    const int lane = tid & 63;
    const int w    = tid >> 6;               // 0..7

    // ---- bijective XCD swizzle (nwg=228, q=28, r=4), A-panel-major ----
    const int lin  = blockIdx.y * gridDim.x + blockIdx.x;   // 0..227
    const int xcd  = lin & 7;
    const int sub  = lin >> 3;
    const int wgid = (xcd < 4 ? xcd * 29 : 4 * 29 + (xcd - 4) * 28) + sub;
    const int m0   = (wgid / 6) * 256;
    const int n0   = (wgid % 6) * 256;

    // ---- staging geometry: thread covers rows tr+{0,64,128,192}, 16B grp ----
    const int tr  = tid >> 3;                        // 0..63
    const int swz = ((tid & 7) ^ (tr & 7)) << 3;     // pre-swizzled col (f16)
    const _Float16* Ap = A + (size_t)(m0 + tr) * LDA + swz;
    const _Float16* Bp = B + (size_t)(n0 + tr) * LDB + swz;
    const int ldsbase = w << 9;                      // wave slot (f16) per round

    auto stage = [&](int buf, int kAb, int kBb) {
        _Float16* L = &lds[buf][0];
        #pragma unroll
        for (int h = 0; h < 2; ++h) {
            #pragma unroll
            for (int r = 0; r < 2; ++r) {
                const int ro = h * 128 + r * 64;
                gload16(Ap + (size_t)ro * LDA + kAb, L + h * 8192 + r * 4096 + ldsbase);
                gload16(Bp + (size_t)ro * LDB + kBb, L + 16384 + h * 8192 + r * 4096 + ldsbase);
            }
        }
    };

    // ---- fragment read (XOR-unswizzle) ----
    const int lb = lane & 15;
    const int lq = lane >> 4;
    auto frag = [&](const _Float16* base, int row0, int ks) -> half8 {
        const int row = row0 + lb;                   // row0 multiple of 16
        const int kg  = ks * 4 + lq;                 // logical 8-f16 k-group
        return *(const half8*)&base[row * 64 + ((kg ^ (row & 7)) << 3)];
    };

    const int wm = (w >> 2) * 128;                   // wave M offset in tile
    const int wn = (w & 3) * 64;                     // wave N offset in tile

    f32x4 acc[8][4];
    #pragma unroll
    for (int i = 0; i < 8; ++i)
        #pragma unroll
        for (int j = 0; j < 4; ++j)
            #pragma unroll
            for (int r = 0; r < 4; ++r) acc[i][j][r] = 0.f;

    half8 aL[4][2], aH[4][2], bA[2][2], bB[2][2];

#define SYNC_LG() do {                                                          \
    asm volatile("s_waitcnt lgkmcnt(0)" ::: "memory");                          \
    __builtin_amdgcn_s_barrier();                                               \
    __builtin_amdgcn_sched_barrier(0);                                          \
} while (0)
#define SYNC_LGVM() do {                                                        \
    asm volatile("s_waitcnt lgkmcnt(0)" ::: "memory");                          \
    asm volatile("s_waitcnt vmcnt(0)" ::: "memory");                            \
    __builtin_amdgcn_s_barrier();                                               \
    __builtin_amdgcn_sched_barrier(0);                                          \
} while (0)
#define PHASE_MFMA(AF, BF, MO, NO) do {                                         \
    __builtin_amdgcn_s_setprio(1);                                              \
    _Pragma("unroll")                                                           \
    for (int i = 0; i < 4; ++i) {                                               \
        _Pragma("unroll")                                                       \
        for (int j = 0; j < 2; ++j) {                                           \
            _Pragma("unroll")                                                   \
            for (int ks = 0; ks < 2; ++ks)                                      \
                acc[(MO) + i][(NO) + j] =                                       \
                    __builtin_amdgcn_mfma_f32_16x16x32_f16(                     \
                        AF[i][ks], BF[j][ks], acc[(MO) + i][(NO) + j], 0, 0, 0);\
        }                                                                       \
    }                                                                           \
    __builtin_amdgcn_s_setprio(0);                                              \
} while (0)

    // ---- prologue: stage tile 0 -> buf 0; preload aL, bA ----
    stage(0, 0, 0);
    asm volatile("s_waitcnt vmcnt(0)" ::: "memory");
    __builtin_amdgcn_s_barrier();
    __builtin_amdgcn_sched_barrier(0);
    #pragma unroll
    for (int i = 0; i < 4; ++i) {
        aL[i][0] = frag(&lds[0][0], wm + i * 16, 0);
        aL[i][1] = frag(&lds[0][0], wm + i * 16, 1);
    }
    #pragma unroll
    for (int j = 0; j < 2; ++j) {
        bA[j][0] = frag(&lds[0][16384], wn + j * 16, 0);
        bA[j][1] = frag(&lds[0][16384], wn + j * 16, 1);
    }

    for (int t = 0; t < NT; ++t) {
        const _Float16* sA  = &lds[t & 1][0];
        const _Float16* sB  = &lds[t & 1][16384];
        const _Float16* sAn = &lds[(t + 1) & 1][0];
        const _Float16* sBn = &lds[(t + 1) & 1][16384];

        // P0: stage(t+1); read bB(cur); MFMA aL*bA -> q00
        SYNC_LG();
        if (t + 1 < NT) {
            const int kk  = (t + 1) * 64;
            const int kAb = (kk < 2048) ? kk : ((kk < 3072) ? kk - 2048 : kk - 1024);
            const int kBb = (kk < 1024) ? kk : kk - 1024;
            stage((t + 1) & 1, kAb, kBb);
        }
        #pragma unroll
        for (int j = 0; j < 2; ++j) {
            bB[j][0] = frag(sB, wn + 32 + j * 16, 0);
            bB[j][1] = frag(sB, wn + 32 + j * 16, 1);
        }
        PHASE_MFMA(aL, bA, 0, 0);

        // P1: read aH(cur); MFMA aL*bB -> q01
        SYNC_LG();
        #pragma unroll
        for (int i = 0; i < 4; ++i) {
            aH[i][0] = frag(sA, wm + 64 + i * 16, 0);
            aH[i][1] = frag(sA, wm + 64 + i * 16, 1);
        }
        PHASE_MFMA(aL, bB, 0, 2);

        // P2: drain stage(t+1); read next-tile aL; MFMA aH*bA -> q10
        SYNC_LGVM();
        #pragma unroll
        for (int i = 0; i < 4; ++i) {
            aL[i][0] = frag(sAn, wm + i * 16, 0);
            aL[i][1] = frag(sAn, wm + i * 16, 1);
        }
        PHASE_MFMA(aH, bA, 4, 0);

        // P3: read next-tile bA; MFMA aH*bB -> q11
        SYNC_LG();
        #pragma unroll
        for (int j = 0; j < 2; ++j) {
            bA[j][0] = frag(sBn, wn + j * 16, 0);
            bA[j][1] = frag(sBn, wn + j * 16, 1);
        }
        PHASE_MFMA(aH, bB, 4, 2);
    }
#undef SYNC_LG
#undef SYNC_LGVM
#undef PHASE_MFMA

    #pragma unroll
    for (int mi = 0; mi < 8; ++mi) {
        #pragma unroll
        for (int ni = 0; ni < 4; ++ni) {
            #pragma unroll
            for (int r = 0; r < 4; ++r) {
                const int row = m0 + wm + mi * 16 + (lane >> 4) * 4 + r;
                const int col = n0 + wn + ni * 16 + (lane & 15);
                Out[(size_t)row * LDO + col] = (_Float16)acc[mi][ni][r];
            }
        }
    }
}

// ---------------------------------------------------------------------------
// Mix kernel (one 64-object chunk), split precision, xcast fused.
// ---------------------------------------------------------------------------
__global__ __launch_bounds__(256, 2)
void mix_kernel(const float* __restrict__ hid, const float* __restrict__ S,
                const _Float16* __restrict__ MTh, const _Float16* __restrict__ MTl,
                const _Float16* __restrict__ Mrh, const _Float16* __restrict__ Mrl,
                _Float16* __restrict__ AVH, int cbase)
{
    __shared__ _Float16 sxh[64 * KLDS];
    __shared__ _Float16 sxl[64 * KLDS];
    const int n  = blockIdx.x;
    const int h0 = blockIdx.y * 64;
    const int tid = threadIdx.x;

    #pragma unroll
    for (int i = 0; i < 5; ++i) {
        const int s  = tid + 256 * i;          // 0..1279
        const int c  = s >> 3;                 // 0..159
        const int hg = s & 7;
        half8 oh, ol;
        if (c < C_) {
            const float* hp = &hid[(size_t)(cbase + n * C_ + c) * H_ + h0 + hg * 8];
            const float* sp = &S[c * H_ + h0 + hg * 8];
            half8 hh;
            #pragma unroll
            for (int j = 0; j < 8; ++j) {
                const float hv = hp[j];
                const float x = sp[j] - hv;
                const _Float16 hi = (_Float16)x;
                oh[j] = hi;
                ol[j] = (_Float16)(x - (float)hi);
                hh[j] = (_Float16)hv;
            }
            *(half8*)&AVH[(size_t)(n * C_ + c) * KA + 2048 + h0 + hg * 8] = hh;
        } else {
            #pragma unroll
            for (int j = 0; j < 8; ++j) { oh[j] = (_Float16)0.f; ol[j] = (_Float16)0.f; }
        }
        #pragma unroll
        for (int j = 0; j < 8; ++j) {
            sxh[(hg * 8 + j) * KLDS + c] = oh[j];
            sxl[(hg * 8 + j) * KLDS + c] = ol[j];
        }
    }
    __syncthreads();

    const int lane = tid & 63;
    const int w    = tid >> 6;
    const _Float16* Mhi = (w >> 1) ? Mrh : MTh;
    const _Float16* Mlo = (w >> 1) ? Mrl : MTl;
    const int hb = (w & 1) * 32;

    f32x4 acc[10][2];
    #pragma unroll
    for (int i = 0; i < 10; ++i)
        #pragma unroll
        for (int j = 0; j < 2; ++j)
            #pragma unroll
            for (int r = 0; r < 4; ++r) acc[i][j][r] = 0.f;

    #pragma unroll
    for (int pass = 0; pass < 3; ++pass) {
        const _Float16* Ma = (pass == 2) ? Mlo : Mhi;
        const _Float16* X  = (pass == 1) ? sxl : sxh;
        #pragma unroll
        for (int kk = 0; kk < 5; ++kk) {
            const int k0 = kk * 32;
            half8 bf[2];
            #pragma unroll
            for (int ht = 0; ht < 2; ++ht)
                bf[ht] = *(const half8*)&X[(hb + ht * 16 + (lane & 15)) * KLDS + k0 + 8 * (lane >> 4)];
            #pragma unroll
            for (int dt = 0; dt < 10; ++dt) {
                half8 af = *(const half8*)&Ma[(dt * 16 + (lane & 15)) * KPAD + k0 + 8 * (lane >> 4)];
                acc[dt][0] = __builtin_amdgcn_mfma_f32_16x16x32_f16(af, bf[0], acc[dt][0], 0, 0, 0);
                acc[dt][1] = __builtin_amdgcn_mfma_f32_16x16x32_f16(af, bf[1], acc[dt][1], 0, 0, 0);
            }
        }
    }

    const int mixoff = (w >> 1) * 512;
    #pragma unroll
    for (int dt = 0; dt < 10; ++dt) {
        #pragma unroll
        for (int ht = 0; ht < 2; ++ht) {
            #pragma unroll
            for (int r = 0; r < 4; ++r) {
                const int d = dt * 16 + (lane >> 4) * 4 + r;
                if (d < C_) {
                    const int h = h0 + hb + ht * 16 + (lane & 15);
                    const float v = acc[dt][ht][r];
                    const _Float16 hi = (_Float16)v;
                    const _Float16 lo = (_Float16)(v - (float)hi);
                    _Float16* rowp = AVH + (size_t)(n * C_ + d) * KA + mixoff + h;
                    rowp[0]    = hi;
                    rowp[1024] = lo;
                }
            }
        }
    }
}

// --------------------------- small kernels ---------------------------------

__global__ void k_sreduce(const float* __restrict__ hid, float* __restrict__ Stmp)
{
    const int c  = blockIdx.x;      // 151
    const int g  = blockIdx.y;      // 8
    const int hw = threadIdx.x;     // 64
    const float* p = hid + (size_t)c * H_ + hw * 8;
    float s[8];
    #pragma unroll
    for (int j = 0; j < 8; ++j) s[j] = 0.f;
    const size_t stride = (size_t)C_ * H_;
    for (int n = g * 32; n < g * 32 + 32; ++n) {
        f32x4 a = *(const f32x4*)(p + (size_t)n * stride);
        f32x4 b = *(const f32x4*)(p + (size_t)n * stride + 4);
        #pragma unroll
        for (int j = 0; j < 4; ++j) { s[j] += a[j]; s[4 + j] += b[j]; }
    }
    float* o = Stmp + (size_t)g * (C_ * H_) + c * H_ + hw * 8;
    *(f32x4*)o       = f32x4{s[0], s[1], s[2], s[3]};
    *(f32x4*)(o + 4) = f32x4{s[4], s[5], s[6], s[7]};
}

__global__ void k_sfold(const float* __restrict__ Stmp, float* __restrict__ S)
{
    const int idx = blockIdx.x * 256 + threadIdx.x;   // 77312
    float s = 0.f;
    #pragma unroll
    for (int g = 0; g < 8; ++g) s += Stmp[(size_t)g * (C_ * H_) + idx];
    S[idx] = s;
}

__global__ void k_ew1(_Float16* __restrict__ pre, const float* __restrict__ hid,
                      const float* __restrict__ bz, const float* __restrict__ br, int cbase)
{
    const int idx = blockIdx.x * 256 + threadIdx.x;   // CH*128
    const unsigned r = idx >> 7;
    const int o4 = (idx & 127) << 2;
    const size_t base = (size_t)r * 1536;
    half4 zp = *(const half4*)&pre[base + o4];
    half4 rp = *(const half4*)&pre[base + 512 + o4];
    f32x4 hd = *(const f32x4*)&hid[(size_t)(cbase + r) * H_ + o4];
    f32x4 bz4 = *(const f32x4*)&bz[o4];
    f32x4 br4 = *(const f32x4*)&br[o4];
    half4 zs, rh;
    #pragma unroll
    for (int j = 0; j < 4; ++j) {
        float z = sigm((float)zp[j] + bz4[j]);
        float rr = sigm((float)rp[j] + br4[j]);
        zs[j] = (_Float16)z;
        rh[j] = (_Float16)(rr * hd[j]);
    }
    *(half4*)&pre[base + o4] = zs;
    *(half4*)&pre[base + 512 + o4] = rh;
}

// EW2: hv = tanh(pre_w5 + p5a + p5b + b5); h = (1-z)h + z*hv -> hid (f32)
__global__ void k_ew2(const _Float16* __restrict__ pre, const _Float16* __restrict__ p5a,
                      const _Float16* __restrict__ p5b,
                      float* __restrict__ hid, const float* __restrict__ b5, int cbase)
{
    const int idx = blockIdx.x * 256 + threadIdx.x;   // CH*128
    const unsigned r = idx >> 7;
    const int o4 = (idx & 127) << 2;
    const size_t base = (size_t)r * 1536;
    half4 w5 = *(const half4*)&pre[base + 1024 + o4];
    half4 pa = *(const half4*)&p5a[(size_t)r * H_ + o4];
    half4 pb = *(const half4*)&p5b[(size_t)r * H_ + o4];
    half4 zz = *(const half4*)&pre[base + o4];
    f32x4 hd = *(const f32x4*)&hid[(size_t)(cbase + r) * H_ + o4];
    f32x4 b54 = *(const f32x4*)&b5[o4];
    #pragma unroll
    for (int j = 0; j < 4; ++j) {
        float t = tanhf((float)w5[j] + (float)pa[j] + (float)pb[j] + b54[j]);
        float z = (float)zz[j];
        hd[j] = (1.f - z) * hd[j] + z * t;
    }
    *(f32x4*)&hid[(size_t)(cbase + r) * H_ + o4] = hd;
}

// --------------------------- prep kernels ----------------------------------

// Wbig [1536, 2560]: row op=(g*512+o): [0,1024)=Wg_hi; [1024,2048)=Wg_lo;
// [2048,2560)=Ug (0 for g=2).
__global__ void prep_wbig(const float* w3w, const float* w3u,
                          const float* w4w, const float* w4u,
                          const float* w5w, const float* w5u,
                          _Float16* __restrict__ Wbig)
{
    const int idx = blockIdx.x * 256 + threadIdx.x;   // 1536*2560
    const int op = idx / KB;
    const int j = idx - op * KB;
    const int g = op >> 9, o = op & 511;
    const float* ww = (g == 0) ? w3w : (g == 1) ? w4w : w5w;
    const float* wu = (g == 0) ? w3u : (g == 1) ? w4u : w5u;
    _Float16 out;
    if (j < 1024) {
        out = (_Float16)ww[o * 1024 + j];
    } else if (j < 2048) {
        const float v = ww[o * 1024 + (j - 1024)];
        const _Float16 hi = (_Float16)v;
        out = (_Float16)(v - (float)hi);
    } else {
        out = (g < 2) ? (_Float16)wu[o * 512 + (j - 2048)] : (_Float16)0.f;
    }
    Wbig[idx] = out;
}

__global__ void prep_m(const float* __restrict__ matrix,
                       _Float16* __restrict__ MTh, _Float16* __restrict__ MTl,
                       _Float16* __restrict__ Mrh, _Float16* __restrict__ Mrl)
{
    const int idx = blockIdx.x * 256 + threadIdx.x;   // KPAD*KPAD
    const int d = idx / KPAD, c = idx - d * KPAD;
    float vT = 0.f, vR = 0.f;
    if (d < C_ && c < C_) { vT = matrix[c * C_ + d]; vR = matrix[d * C_ + c]; }
    const _Float16 th = (_Float16)vT;
    const _Float16 rh = (_Float16)vR;
    MTh[idx] = th; MTl[idx] = (_Float16)(vT - (float)th);
    Mrh[idx] = rh; Mrl[idx] = (_Float16)(vR - (float)rh);
}

__global__ void prep_wout(const float* __restrict__ wout,
                          _Float16* __restrict__ WL, _Float16* __restrict__ WR)
{
    const int idx = blockIdx.x * 256 + threadIdx.x;   // 512*512
    const int o = idx >> 9, j = idx & 511;
    WL[idx] = (_Float16)wout[o * 1024 + j];
    WR[idx] = (_Float16)wout[o * 1024 + 512 + j];
}

// only the 151 real rows; rows 151..255 stay poisoned (never read downstream)
__global__ void prep_wcls(const float* __restrict__ wcls, _Float16* __restrict__ w16)
{
    const int k = blockIdx.x * 256 + threadIdx.x;   // 77312
    const int d = blockIdx.y;                        // 0..150
    w16[(size_t)d * (C_ * H_) + k] = (_Float16)wcls[(size_t)d * (C_ * H_) + k];
}

__global__ void k_cast(const float* __restrict__ src, _Float16* __restrict__ dst, int n)
{
    const int i = blockIdx.x * 256 + threadIdx.x;
    if (i < n) dst[i] = (_Float16)src[i];
}

__global__ void prep_bias(const float* b3w, const float* b3u, const float* b4w,
                          const float* b4u, const float* b5w, const float* b5u,
                          float* bz, float* br, float* b5)
{
    const int i = threadIdx.x;   // 512 threads
    bz[i] = b3w[i] + b3u[i];
    br[i] = b4w[i] + b4u[i];
    b5[i] = b5w[i] + b5u[i];
}

__global__ void prep_hid(const float* __restrict__ input, float* __restrict__ hid)
{
    const int idx = blockIdx.x * 256 + threadIdx.x;   // NR*128
    const unsigned row = idx >> 7;
    const int h4 = (idx & 127) << 2;
    const unsigned n = row / 151u;
    f32x4 v = *(const f32x4*)&input[(size_t)n * H_ + h4];
    *(f32x4*)&hid[(size_t)row * H_ + h4] = v;
}

__global__ void k_reduce(const float* __restrict__ partial, const float* __restrict__ bcls,
                         float* __restrict__ out)
{
    const int idx = blockIdx.x * 256 + threadIdx.x;   // NR
    const unsigned n = (unsigned)idx / 151u;
    const unsigned d = (unsigned)idx - n * 151u;
    float s = 0.f;
    for (int z = 0; z < C_; ++z)
        s += partial[(size_t)z * (NOBJ * 256) + n * 256 + d];
    out[idx] = s + bcls[d];
}

// ---------------------------------------------------------------------------

extern "C" void kernel_launch(void* const* d_in, const int* in_sizes, int n_in,
                              void* d_out, int out_size, void* d_ws, size_t ws_size,
                              hipStream_t stream)
{
    const float* input  = (const float*)d_in[0];
    const float* matrix = (const float*)d_in[1];
    const float* w3w = (const float*)d_in[2];
    const float* b3w = (const float*)d_in[3];
    const float* w3u = (const float*)d_in[4];
    const float* b3u = (const float*)d_in[5];
    const float* w4w = (const float*)d_in[6];
    const float* b4w = (const float*)d_in[7];
    const float* w4u = (const float*)d_in[8];
    const float* b4u = (const float*)d_in[9];
    const float* w5w = (const float*)d_in[10];
    const float* b5w = (const float*)d_in[11];
    const float* w5u = (const float*)d_in[12];
    const float* b5u = (const float*)d_in[13];
    const float* wout = (const float*)d_in[14];
    const float* bout = (const float*)d_in[15];
    const float* wcls = (const float*)d_in[16];
    const float* bcls = (const float*)d_in[17];
    float* obj = (float*)d_out;

    char* ws = (char*)d_ws;
    size_t off = 0;
    auto take = [&](size_t bytes) -> char* {
        off = (off + 255) & ~(size_t)255;
        char* p = ws + off;
        off += bytes;
        return p;
    };

    _Float16* Wbig  = (_Float16*)take((size_t)1536 * KB * 2);     //  7.86 MB
    _Float16* MTh   = (_Float16*)take((size_t)KPAD * KPAD * 2);
    _Float16* MTl   = (_Float16*)take((size_t)KPAD * KPAD * 2);
    _Float16* Mrh   = (_Float16*)take((size_t)KPAD * KPAD * 2);
    _Float16* Mrl   = (_Float16*)take((size_t)KPAD * KPAD * 2);
    _Float16* W5u16 = (_Float16*)take((size_t)512 * 512 * 2);
    _Float16* WL16  = (_Float16*)take((size_t)512 * 512 * 2);
    _Float16* WR16  = (_Float16*)take((size_t)512 * 512 * 2);
    _Float16* in16  = (_Float16*)take((size_t)256 * 512 * 2);
    float*    bz    = (float*)take(512 * 4);
    float*    br    = (float*)take(512 * 4);
    float*    b5    = (float*)take(512 * 4);
    float*    Stmp  = (float*)take((size_t)8 * C_ * H_ * 4);      //  2.47 MB
    float*    S32   = (float*)take((size_t)C_ * H_ * 4);
    float*    base  = (float*)take((size_t)256 * 512 * 4);
    float*    hid32 = (float*)take((size_t)NR * H_ * 4);          // 79.17 MB
    _Float16* AVH   = (_Float16*)take((size_t)CHP * KA * 2);      // 49.81 MB
    _Float16* prec  = (_Float16*)take((size_t)CHP * 1536 * 2);    // 29.88 MB
    // time-based aliases:
    _Float16* p5u = AVH;                 // 2 split-K halves: 2*CHP*512*2 = 19.9 MB < AVH
    _Float16* OUT16 = AVH;               // epilogue out (after loop)
    _Float16* Wcls16 = (_Float16*)hid32; // hid dead after epilogue GEMM
    float* partial = (float*)((char*)hid32 + (size_t)NOBJ * C_ * H_ * 2);

    (void)in_sizes; (void)n_in; (void)out_size; (void)ws_size;

    // ---- prep ----
    prep_wbig<<<dim3((1536 * KB) / 256), 256, 0, stream>>>(w3w, w3u, w4w, w4u, w5w, w5u, Wbig);
    prep_m<<<dim3((KPAD * KPAD) / 256), 256, 0, stream>>>(matrix, MTh, MTl, Mrh, Mrl);
    k_cast<<<dim3((512 * 512) / 256), 256, 0, stream>>>(w5u, W5u16, 512 * 512);
    prep_wout<<<dim3((512 * 512) / 256), 256, 0, stream>>>(wout, WL16, WR16);
    k_cast<<<dim3((256 * 512) / 256), 256, 0, stream>>>(input, in16, 256 * 512);
    prep_bias<<<dim3(1), 512, 0, stream>>>(b3w, b3u, b4w, b4u, b5w, b5u, bz, br, b5);
    prep_hid<<<dim3((NR * 128) / 256), 256, 0, stream>>>(input, hid32);
    gemm_kernel<0, _Float16, false><<<dim3(2, 4, 1), 256, 0, stream>>>(
        in16, 512, WR16, 512, base, 512, nullptr, nullptr, 512, 0);

    // ---- 3 GGNN steps, 4 object-chunks each ----
    for (int t = 0; t < 3; ++t) {
        k_sreduce<<<dim3(C_, 8), 64, 0, stream>>>(hid32, Stmp);
        k_sfold<<<dim3((C_ * H_) / 256), 256, 0, stream>>>(Stmp, S32);
        for (int cc = 0; cc < 4; ++cc) {
            const int cbase = cc * CH;
            mix_kernel<<<dim3(NCH, 8), 256, 0, stream>>>(
                hid32, S32, MTh, MTl, Mrh, Mrl, AVH, cbase);
            // gate GEMM (virtual K=3584 over physical B 2560), 256x256 pipelined
            gemm256<<<dim3(CHP / 256, 1536 / 256, 1), 512, 0, stream>>>(
                AVH, Wbig, prec);
            k_ew1<<<dim3((CH * 128) / 256), 256, 0, stream>>>(prec, hid32, bz, br, cbase);
            // p5u = (r*h) @ W5u^T, split-K=2 (f16 partials summed in ew2)
            gemm_kernel<1, _Float16, false><<<dim3(CHP / 128, 4, 2), 256, 0, stream>>>(
                prec + 512, 1536, W5u16, 512, p5u, 512, nullptr, nullptr, 256, CHP * 512);
            k_ew2<<<dim3((CH * 128) / 256), 256, 0, stream>>>(
                prec, p5u, p5u + (size_t)CHP * 512, hid32, b5, cbase);
        }
    }

    // ---- epilogue: OUT = relu(hid @ WL^T + base[n] + bout)  (A is f32) ----
    gemm_kernel<2, float, false><<<dim3(NR / 128, 512 / 128, 1), 256, 0, stream>>>(
        hid32, 512, WL16, 512, OUT16, 512, bout, base, 512, 0);

    // ---- classifier: split-K over 151 chunks of 512 ----
    prep_wcls<<<dim3((C_ * H_) / 256, C_), 256, 0, stream>>>(wcls, Wcls16);
    gemm_kernel<0, _Float16, false><<<dim3(NOBJ / 128, 256 / 128, C_), 256, 0, stream>>>(
        OUT16, C_ * H_, Wcls16, C_ * H_, partial, 256, nullptr, nullptr, 512, NOBJ * 256);
    k_reduce<<<dim3(NR / 256), 256, 0, stream>>>(partial, bcls, obj);
}

// Round 3
// 2416.268 us; speedup vs baseline: 1.0749x; 1.0521x over previous
//
#include <hip/hip_runtime.h>

// ---------------------------------------------------------------------------
// GGNN-obj (N=256, C=151, H=512, T=3). Split-f16 (hi+lo) MFMA on the
// recurrent path, f32 hidden master.
// R12->R13: gate GEMM now uses COUNTED vmcnt (T4), never a full drain in the
// main loop. Stage order [A0,A128,B0,B64,B128,B192,A64,A192]; per tile only
// two sync points: {vmcnt(2); barrier} before superphase-0 (reads aL,bA,bB;
// MFMA q00,q01) and {vmcnt(8); barrier} before superphase-1 (reads aH; MFMA
// q10,q11). Counted wait + barrier = cross-wave visibility (each wave
// verified its own slice). Loads get ~1 full tile of flight; waves drift
// within superphases so ds_reads overlap other waves' MFMAs. Math order per
// output element unchanged -> bit-identical.
// ---------------------------------------------------------------------------

#define C_     151
#define H_     512
#define NOBJ   256
#define NR     38656      // NOBJ * C_
#define NCH    64         // objects per chunk
#define CH     9664       // NCH * C_
#define CHP    9728       // CH padded to 256-multiple (38 tiles of 256)
#define KPAD   160        // C_ padded to 32-multiple
#define KLDS   168        // LDS row stride for transposed x tiles
#define KA     2560       // A cols in gate GEMM: [av_hi 1024 | av_lo 1024 | h 512]
#define KV     3584       // virtual K: ah*Wh + al*Wh + ah*Wl + h*Wu
#define KB     2560       // physical B cols: [Wh 1024 | Wl 1024 | Wu 512]

typedef _Float16 half8 __attribute__((ext_vector_type(8)));
typedef _Float16 half4 __attribute__((ext_vector_type(4)));
typedef float    f32x4 __attribute__((ext_vector_type(4)));

__device__ __forceinline__ float sigm(float x) { return 1.f / (1.f + expf(-x)); }

__device__ __forceinline__ void gload16(const void* g, void* l) {
    __builtin_amdgcn_global_load_lds(
        (const __attribute__((address_space(1))) void*)g,
        (__attribute__((address_space(3))) void*)l, 16, 0, 0);
}

// Staging swizzle for the 128x32 gemm_kernel path (unchanged):
__device__ __forceinline__ int kqswz(int s) {
    return 8 * (((s & 3) + 8 - ((s >> 2) & 3) - ((s >> 4) & 3)) & 3);
}
__device__ __forceinline__ int fraswz(int lane) {
    const int lb = lane & 15;
    return lb * 32 + 8 * (((lane >> 4) + lb + (lb >> 2)) & 3);
}

__device__ __forceinline__ half8 loadA8(const _Float16* p) { return *(const half8*)p; }
__device__ __forceinline__ half8 loadA8(const float* p) {
    f32x4 a = *(const f32x4*)p;
    f32x4 b = *(const f32x4*)(p + 4);
    half8 o;
    #pragma unroll
    for (int j = 0; j < 4; ++j) { o[j] = (_Float16)a[j]; o[4 + j] = (_Float16)b[j]; }
    return o;
}

// ---------------------------------------------------------------------------
// 128x128-tile GEMM (256 thr, 16x16x32): Out[m,n] = sum_k A[m,k]*B[n,k].
// OP: 0 = f32 store, 1 = f16 store, 2 = relu(v+bias[col]+bias2[...]) -> f16
// ---------------------------------------------------------------------------
template<int OP, typename AT, bool DUPK>
__global__ __launch_bounds__(256, 2)
void gemm_kernel(const AT* __restrict__ A, int lda,
                 const _Float16* __restrict__ B, int ldb,
                 void* __restrict__ Out, int ldo,
                 const float* __restrict__ bias,
                 const float* __restrict__ bias2,
                 int kchunk, int chunkStride)
{
    constexpr bool A16 = (sizeof(AT) == 2);
    __shared__ _Float16 sA[128 * 32];
    __shared__ _Float16 sB[128 * 32];
    const int tid  = threadIdx.x;
    const int lane = tid & 63;
    const int w    = tid >> 6;
    const int m0   = blockIdx.x * 128;
    const int n0   = blockIdx.y * 128;
    const int kbase = blockIdx.z * kchunk;

    const int s0 = tid, s1 = tid + 256;
    const AT* Ap0 = A + (size_t)(m0 + (s0 >> 2)) * lda + kqswz(s0);
    const AT* Ap1 = A + (size_t)(m0 + (s1 >> 2)) * lda + kqswz(s1);
    const _Float16* Bp0 = B + (size_t)(n0 + (s0 >> 2)) * ldb + kbase + kqswz(s0);
    const _Float16* Bp1 = B + (size_t)(n0 + (s1 >> 2)) * ldb + kbase + kqswz(s1);
    const int la0 = 8 * s0;
    const int la1 = 8 * s1;
    _Float16* lA0 = &sA[w * 512];
    _Float16* lA1 = &sA[2048 + w * 512];
    _Float16* lB0 = &sB[w * 512];
    _Float16* lB1 = &sB[2048 + w * 512];

    f32x4 acc[4][4];
    #pragma unroll
    for (int i = 0; i < 4; ++i)
        #pragma unroll
        for (int j = 0; j < 4; ++j)
            #pragma unroll
            for (int r = 0; r < 4; ++r) acc[i][j][r] = 0.f;

    const int mrow = (w >> 1) * 64;
    const int ncol = (w & 1) * 64;
    const int fra  = fraswz(lane);

    for (int k0 = 0; k0 < kchunk; k0 += 32) {
        int kA;
        if (DUPK) kA = (k0 < 2048) ? k0 : ((k0 < 3072) ? k0 - 2048 : k0 - 1024);
        else      kA = kbase + k0;
        if constexpr (A16) {
            __syncthreads();
            gload16(Ap0 + kA, lA0);
            gload16(Ap1 + kA, lA1);
            gload16(Bp0 + k0, lB0);
            gload16(Bp1 + k0, lB1);
            __syncthreads();
        } else {
            half8 va0 = loadA8(Ap0 + kA);
            half8 va1 = loadA8(Ap1 + kA);
            half8 vb0 = *(const half8*)(Bp0 + k0);
            half8 vb1 = *(const half8*)(Bp1 + k0);
            __syncthreads();
            *(half8*)&sA[la0] = va0;
            *(half8*)&sA[la1] = va1;
            *(half8*)&sB[la0] = vb0;
            *(half8*)&sB[la1] = vb1;
            __syncthreads();
        }
        half8 af[4], bf[4];
        #pragma unroll
        for (int i = 0; i < 4; ++i)
            af[i] = *(const half8*)&sA[(mrow + i * 16) * 32 + fra];
        #pragma unroll
        for (int i = 0; i < 4; ++i)
            bf[i] = *(const half8*)&sB[(ncol + i * 16) * 32 + fra];
        #pragma unroll
        for (int mi = 0; mi < 4; ++mi)
            #pragma unroll
            for (int ni = 0; ni < 4; ++ni)
                acc[mi][ni] = __builtin_amdgcn_mfma_f32_16x16x32_f16(af[mi], bf[ni], acc[mi][ni], 0, 0, 0);
    }

    const size_t zoff = (size_t)blockIdx.z * (size_t)chunkStride;
    #pragma unroll
    for (int mi = 0; mi < 4; ++mi) {
        #pragma unroll
        for (int ni = 0; ni < 4; ++ni) {
            #pragma unroll
            for (int r = 0; r < 4; ++r) {
                const int row = m0 + mrow + mi * 16 + (lane >> 4) * 4 + r;
                const int col = n0 + ncol + ni * 16 + (lane & 15);
                float v = acc[mi][ni][r];
                const size_t o = zoff + (size_t)row * ldo + col;
                if (OP == 0) {
                    ((float*)Out)[o] = v;
                } else if (OP == 1) {
                    ((_Float16*)Out)[o] = (_Float16)v;
                } else {
                    const unsigned n = (unsigned)row / 151u;
                    v += bias[col] + bias2[n * 512u + col];
                    v = v > 0.f ? v : 0.f;
                    ((_Float16*)Out)[o] = (_Float16)v;
                }
            }
        }
    }
}

// ---------------------------------------------------------------------------
// 256x256-tile gate GEMM, counted-vmcnt 2-superphase schedule.
// 512 thr = 8 waves (2M x 4N), per-wave 128x64, BK=64, double-buffered LDS.
// Stage order: [A0,A128 | B0,B64,B128,B192 | A64,A192] -> first 6 loads are
// exactly what SP0 needs (aL rows 0-63/128-191, all bA/bB rows), last 2 what
// SP1 needs (aH rows 64-127/192-255).
// Tile t: {vmcnt(2); barrier} -> stage(t+1) -> read aL,bA,bB -> MFMA q00,q01
//         {vmcnt(8); barrier} -> read aH -> MFMA q10,q11.
// vmcnt(2): first-6 of tile t landed (2 younger = A64/A192 of t).
// vmcnt(8): A64/A192 of t landed (8 younger = tile t+1's stage).
// Counted wait + barrier = cross-wave visibility. Loads fly ~1 full tile.
// XOR-swizzled LDS (pre-swizzled global source) -> conflict-free ds_read_b128.
// Bijective XCD swizzle, A-panel-major (FETCH 179->85 MB measured R12).
// ---------------------------------------------------------------------------
__global__ __launch_bounds__(512, 2)
void gemm256(const _Float16* __restrict__ A, const _Float16* __restrict__ B,
             _Float16* __restrict__ Out)
{
    constexpr int LDA = KA;       // 2560
    constexpr int LDB = KB;       // 2560
    constexpr int LDO = 1536;
    constexpr int NT  = KV / 64;  // 56 K-tiles
    __shared__ _Float16 lds[2][32768];   // [buf][ A 256x64 | B 256x64 ]  128 KB

    const int tid  = threadIdx.x;
    const int lane = tid & 63;
    const int w    = tid >> 6;               // 0..7

    // ---- bijective XCD swizzle (nwg=228, q=28, r=4), A-panel-major ----
    const int lin  = blockIdx.y * gridDim.x + blockIdx.x;   // 0..227
    const int xcd  = lin & 7;
    const int sub  = lin >> 3;
    const int wgid = (xcd < 4 ? xcd * 29 : 4 * 29 + (xcd - 4) * 28) + sub;
    const int m0   = (wgid / 6) * 256;
    const int n0   = (wgid % 6) * 256;

    // ---- staging geometry: thread covers rows tr+{0,64,128,192}, 16B grp ----
    const int tr  = tid >> 3;                        // 0..63
    const int swz = ((tid & 7) ^ (tr & 7)) << 3;     // pre-swizzled col (f16)
    const _Float16* Ap = A + (size_t)(m0 + tr) * LDA + swz;
    const _Float16* Bp = B + (size_t)(n0 + tr) * LDB + swz;
    const int ldsbase = w << 9;                      // wave slot (f16) per round

    // issue order matters: first 6 feed SP0, last 2 feed SP1
    auto stage = [&](int buf, int kAb, int kBb) {
        _Float16* L = &lds[buf][0];
        gload16(Ap + kAb,                        L + ldsbase);             // A   0- 63
        gload16(Ap + (size_t)128 * LDA + kAb,    L + 128 * 64 + ldsbase);  // A 128-191
        gload16(Bp + kBb,                        L + 16384 + ldsbase);             // B   0- 63
        gload16(Bp + (size_t)64  * LDB + kBb,    L + 16384 +  64 * 64 + ldsbase);  // B  64-127
        gload16(Bp + (size_t)128 * LDB + kBb,    L + 16384 + 128 * 64 + ldsbase);  // B 128-191
        gload16(Bp + (size_t)192 * LDB + kBb,    L + 16384 + 192 * 64 + ldsbase);  // B 192-255
        gload16(Ap + (size_t)64  * LDA + kAb,    L +  64 * 64 + ldsbase);  // A  64-127
        gload16(Ap + (size_t)192 * LDA + kAb,    L + 192 * 64 + ldsbase);  // A 192-255
    };

    // ---- fragment read (XOR-unswizzle) ----
    const int lb = lane & 15;
    const int lq = lane >> 4;
    auto frag = [&](const _Float16* base, int row0, int ks) -> half8 {
        const int row = row0 + lb;                   // row0 multiple of 16
        const int kg  = ks * 4 + lq;                 // logical 8-f16 k-group
        return *(const half8*)&base[row * 64 + ((kg ^ (row & 7)) << 3)];
    };

    const int wm = (w >> 2) * 128;                   // wave M offset in tile
    const int wn = (w & 3) * 64;                     // wave N offset in tile

    f32x4 acc[8][4];
    #pragma unroll
    for (int i = 0; i < 8; ++i)
        #pragma unroll
        for (int j = 0; j < 4; ++j)
            #pragma unroll
            for (int r = 0; r < 4; ++r) acc[i][j][r] = 0.f;

    half8 aL[4][2], aH[4][2], bA[2][2], bB[2][2];

#define PHASE_MFMA(AF, BF, MO, NO) do {                                         \
    __builtin_amdgcn_s_setprio(1);                                              \
    _Pragma("unroll")                                                           \
    for (int i = 0; i < 4; ++i) {                                               \
        _Pragma("unroll")                                                       \
        for (int j = 0; j < 2; ++j) {                                           \
            _Pragma("unroll")                                                   \
            for (int ks = 0; ks < 2; ++ks)                                      \
                acc[(MO) + i][(NO) + j] =                                       \
                    __builtin_amdgcn_mfma_f32_16x16x32_f16(                     \
                        AF[i][ks], BF[j][ks], acc[(MO) + i][(NO) + j], 0, 0, 0);\
        }                                                                       \
    }                                                                           \
    __builtin_amdgcn_s_setprio(0);                                              \
} while (0)

    // ---- prologue: stage tile 0 -> buf 0 (no wait; SP0's vmcnt covers) ----
    stage(0, 0, 0);

    for (int t = 0; t < NT; ++t) {
        const _Float16* sA = &lds[t & 1][0];
        const _Float16* sB = &lds[t & 1][16384];

        // ---- superphase 0: needs first 6 loads of tile t ----
        asm volatile("s_waitcnt vmcnt(2)" ::: "memory");
        __builtin_amdgcn_s_barrier();
        __builtin_amdgcn_sched_barrier(0);
        if (t + 1 < NT) {
            const int kk  = (t + 1) * 64;
            const int kAb = (kk < 2048) ? kk : ((kk < 3072) ? kk - 2048 : kk - 1024);
            const int kBb = (kk < 1024) ? kk : kk - 1024;
            stage((t + 1) & 1, kAb, kBb);
        }
        #pragma unroll
        for (int i = 0; i < 4; ++i) {
            aL[i][0] = frag(sA, wm + i * 16, 0);
            aL[i][1] = frag(sA, wm + i * 16, 1);
        }
        #pragma unroll
        for (int j = 0; j < 2; ++j) {
            bA[j][0] = frag(sB, wn + j * 16, 0);
            bA[j][1] = frag(sB, wn + j * 16, 1);
        }
        #pragma unroll
        for (int j = 0; j < 2; ++j) {
            bB[j][0] = frag(sB, wn + 32 + j * 16, 0);
            bB[j][1] = frag(sB, wn + 32 + j * 16, 1);
        }
        PHASE_MFMA(aL, bA, 0, 0);
        PHASE_MFMA(aL, bB, 0, 2);

        // ---- superphase 1: needs last 2 loads of tile t (aH rows) ----
        if (t + 1 < NT) asm volatile("s_waitcnt vmcnt(8)" ::: "memory");
        else            asm volatile("s_waitcnt vmcnt(0)" ::: "memory");
        __builtin_amdgcn_s_barrier();
        __builtin_amdgcn_sched_barrier(0);
        #pragma unroll
        for (int i = 0; i < 4; ++i) {
            aH[i][0] = frag(sA, wm + 64 + i * 16, 0);
            aH[i][1] = frag(sA, wm + 64 + i * 16, 1);
        }
        PHASE_MFMA(aH, bA, 4, 0);
        PHASE_MFMA(aH, bB, 4, 2);
    }
#undef PHASE_MFMA

    #pragma unroll
    for (int mi = 0; mi < 8; ++mi) {
        #pragma unroll
        for (int ni = 0; ni < 4; ++ni) {
            #pragma unroll
            for (int r = 0; r < 4; ++r) {
                const int row = m0 + wm + mi * 16 + (lane >> 4) * 4 + r;
                const int col = n0 + wn + ni * 16 + (lane & 15);
                Out[(size_t)row * LDO + col] = (_Float16)acc[mi][ni][r];
            }
        }
    }
}

// ---------------------------------------------------------------------------
// Mix kernel (one 64-object chunk), split precision, xcast fused.
// ---------------------------------------------------------------------------
__global__ __launch_bounds__(256, 2)
void mix_kernel(const float* __restrict__ hid, const float* __restrict__ S,
                const _Float16* __restrict__ MTh, const _Float16* __restrict__ MTl,
                const _Float16* __restrict__ Mrh, const _Float16* __restrict__ Mrl,
                _Float16* __restrict__ AVH, int cbase)
{
    __shared__ _Float16 sxh[64 * KLDS];
    __shared__ _Float16 sxl[64 * KLDS];
    const int n  = blockIdx.x;
    const int h0 = blockIdx.y * 64;
    const int tid = threadIdx.x;

    #pragma unroll
    for (int i = 0; i < 5; ++i) {
        const int s  = tid + 256 * i;          // 0..1279
        const int c  = s >> 3;                 // 0..159
        const int hg = s & 7;
        half8 oh, ol;
        if (c < C_) {
            const float* hp = &hid[(size_t)(cbase + n * C_ + c) * H_ + h0 + hg * 8];
            const float* sp = &S[c * H_ + h0 + hg * 8];
            half8 hh;
            #pragma unroll
            for (int j = 0; j < 8; ++j) {
                const float hv = hp[j];
                const float x = sp[j] - hv;
                const _Float16 hi = (_Float16)x;
                oh[j] = hi;
                ol[j] = (_Float16)(x - (float)hi);
                hh[j] = (_Float16)hv;
            }
            *(half8*)&AVH[(size_t)(n * C_ + c) * KA + 2048 + h0 + hg * 8] = hh;
        } else {
            #pragma unroll
            for (int j = 0; j < 8; ++j) { oh[j] = (_Float16)0.f; ol[j] = (_Float16)0.f; }
        }
        #pragma unroll
        for (int j = 0; j < 8; ++j) {
            sxh[(hg * 8 + j) * KLDS + c] = oh[j];
            sxl[(hg * 8 + j) * KLDS + c] = ol[j];
        }
    }
    __syncthreads();

    const int lane = tid & 63;
    const int w    = tid >> 6;
    const _Float16* Mhi = (w >> 1) ? Mrh : MTh;
    const _Float16* Mlo = (w >> 1) ? Mrl : MTl;
    const int hb = (w & 1) * 32;

    f32x4 acc[10][2];
    #pragma unroll
    for (int i = 0; i < 10; ++i)
        #pragma unroll
        for (int j = 0; j < 2; ++j)
            #pragma unroll
            for (int r = 0; r < 4; ++r) acc[i][j][r] = 0.f;

    #pragma unroll
    for (int pass = 0; pass < 3; ++pass) {
        const _Float16* Ma = (pass == 2) ? Mlo : Mhi;
        const _Float16* X  = (pass == 1) ? sxl : sxh;
        #pragma unroll
        for (int kk = 0; kk < 5; ++kk) {
            const int k0 = kk * 32;
            half8 bf[2];
            #pragma unroll
            for (int ht = 0; ht < 2; ++ht)
                bf[ht] = *(const half8*)&X[(hb + ht * 16 + (lane & 15)) * KLDS + k0 + 8 * (lane >> 4)];
            #pragma unroll
            for (int dt = 0; dt < 10; ++dt) {
                half8 af = *(const half8*)&Ma[(dt * 16 + (lane & 15)) * KPAD + k0 + 8 * (lane >> 4)];
                acc[dt][0] = __builtin_amdgcn_mfma_f32_16x16x32_f16(af, bf[0], acc[dt][0], 0, 0, 0);
                acc[dt][1] = __builtin_amdgcn_mfma_f32_16x16x32_f16(af, bf[1], acc[dt][1], 0, 0, 0);
            }
        }
    }

    const int mixoff = (w >> 1) * 512;
    #pragma unroll
    for (int dt = 0; dt < 10; ++dt) {
        #pragma unroll
        for (int ht = 0; ht < 2; ++ht) {
            #pragma unroll
            for (int r = 0; r < 4; ++r) {
                const int d = dt * 16 + (lane >> 4) * 4 + r;
                if (d < C_) {
                    const int h = h0 + hb + ht * 16 + (lane & 15);
                    const float v = acc[dt][ht][r];
                    const _Float16 hi = (_Float16)v;
                    const _Float16 lo = (_Float16)(v - (float)hi);
                    _Float16* rowp = AVH + (size_t)(n * C_ + d) * KA + mixoff + h;
                    rowp[0]    = hi;
                    rowp[1024] = lo;
                }
            }
        }
    }
}

// --------------------------- small kernels ---------------------------------

__global__ void k_sreduce(const float* __restrict__ hid, float* __restrict__ Stmp)
{
    const int c  = blockIdx.x;      // 151
    const int g  = blockIdx.y;      // 8
    const int hw = threadIdx.x;     // 64
    const float* p = hid + (size_t)c * H_ + hw * 8;
    float s[8];
    #pragma unroll
    for (int j = 0; j < 8; ++j) s[j] = 0.f;
    const size_t stride = (size_t)C_ * H_;
    for (int n = g * 32; n < g * 32 + 32; ++n) {
        f32x4 a = *(const f32x4*)(p + (size_t)n * stride);
        f32x4 b = *(const f32x4*)(p + (size_t)n * stride + 4);
        #pragma unroll
        for (int j = 0; j < 4; ++j) { s[j] += a[j]; s[4 + j] += b[j]; }
    }
    float* o = Stmp + (size_t)g * (C_ * H_) + c * H_ + hw * 8;
    *(f32x4*)o       = f32x4{s[0], s[1], s[2], s[3]};
    *(f32x4*)(o + 4) = f32x4{s[4], s[5], s[6], s[7]};
}

__global__ void k_sfold(const float* __restrict__ Stmp, float* __restrict__ S)
{
    const int idx = blockIdx.x * 256 + threadIdx.x;   // 77312
    float s = 0.f;
    #pragma unroll
    for (int g = 0; g < 8; ++g) s += Stmp[(size_t)g * (C_ * H_) + idx];
    S[idx] = s;
}

__global__ void k_ew1(_Float16* __restrict__ pre, const float* __restrict__ hid,
                      const float* __restrict__ bz, const float* __restrict__ br, int cbase)
{
    const int idx = blockIdx.x * 256 + threadIdx.x;   // CH*128
    const unsigned r = idx >> 7;
    const int o4 = (idx & 127) << 2;
    const size_t base = (size_t)r * 1536;
    half4 zp = *(const half4*)&pre[base + o4];
    half4 rp = *(const half4*)&pre[base + 512 + o4];
    f32x4 hd = *(const f32x4*)&hid[(size_t)(cbase + r) * H_ + o4];
    f32x4 bz4 = *(const f32x4*)&bz[o4];
    f32x4 br4 = *(const f32x4*)&br[o4];
    half4 zs, rh;
    #pragma unroll
    for (int j = 0; j < 4; ++j) {
        float z = sigm((float)zp[j] + bz4[j]);
        float rr = sigm((float)rp[j] + br4[j]);
        zs[j] = (_Float16)z;
        rh[j] = (_Float16)(rr * hd[j]);
    }
    *(half4*)&pre[base + o4] = zs;
    *(half4*)&pre[base + 512 + o4] = rh;
}

// EW2: hv = tanh(pre_w5 + p5a + p5b + b5); h = (1-z)h + z*hv -> hid (f32)
__global__ void k_ew2(const _Float16* __restrict__ pre, const _Float16* __restrict__ p5a,
                      const _Float16* __restrict__ p5b,
                      float* __restrict__ hid, const float* __restrict__ b5, int cbase)
{
    const int idx = blockIdx.x * 256 + threadIdx.x;   // CH*128
    const unsigned r = idx >> 7;
    const int o4 = (idx & 127) << 2;
    const size_t base = (size_t)r * 1536;
    half4 w5 = *(const half4*)&pre[base + 1024 + o4];
    half4 pa = *(const half4*)&p5a[(size_t)r * H_ + o4];
    half4 pb = *(const half4*)&p5b[(size_t)r * H_ + o4];
    half4 zz = *(const half4*)&pre[base + o4];
    f32x4 hd = *(const f32x4*)&hid[(size_t)(cbase + r) * H_ + o4];
    f32x4 b54 = *(const f32x4*)&b5[o4];
    #pragma unroll
    for (int j = 0; j < 4; ++j) {
        float t = tanhf((float)w5[j] + (float)pa[j] + (float)pb[j] + b54[j]);
        float z = (float)zz[j];
        hd[j] = (1.f - z) * hd[j] + z * t;
    }
    *(f32x4*)&hid[(size_t)(cbase + r) * H_ + o4] = hd;
}

// --------------------------- prep kernels ----------------------------------

// Wbig [1536, 2560]: row op=(g*512+o): [0,1024)=Wg_hi; [1024,2048)=Wg_lo;
// [2048,2560)=Ug (0 for g=2).
__global__ void prep_wbig(const float* w3w, const float* w3u,
                          const float* w4w, const float* w4u,
                          const float* w5w, const float* w5u,
                          _Float16* __restrict__ Wbig)
{
    const int idx = blockIdx.x * 256 + threadIdx.x;   // 1536*2560
    const int op = idx / KB;
    const int j = idx - op * KB;
    const int g = op >> 9, o = op & 511;
    const float* ww = (g == 0) ? w3w : (g == 1) ? w4w : w5w;
    const float* wu = (g == 0) ? w3u : (g == 1) ? w4u : w5u;
    _Float16 out;
    if (j < 1024) {
        out = (_Float16)ww[o * 1024 + j];
    } else if (j < 2048) {
        const float v = ww[o * 1024 + (j - 1024)];
        const _Float16 hi = (_Float16)v;
        out = (_Float16)(v - (float)hi);
    } else {
        out = (g < 2) ? (_Float16)wu[o * 512 + (j - 2048)] : (_Float16)0.f;
    }
    Wbig[idx] = out;
}

__global__ void prep_m(const float* __restrict__ matrix,
                       _Float16* __restrict__ MTh, _Float16* __restrict__ MTl,
                       _Float16* __restrict__ Mrh, _Float16* __restrict__ Mrl)
{
    const int idx = blockIdx.x * 256 + threadIdx.x;   // KPAD*KPAD
    const int d = idx / KPAD, c = idx - d * KPAD;
    float vT = 0.f, vR = 0.f;
    if (d < C_ && c < C_) { vT = matrix[c * C_ + d]; vR = matrix[d * C_ + c]; }
    const _Float16 th = (_Float16)vT;
    const _Float16 rh = (_Float16)vR;
    MTh[idx] = th; MTl[idx] = (_Float16)(vT - (float)th);
    Mrh[idx] = rh; Mrl[idx] = (_Float16)(vR - (float)rh);
}

__global__ void prep_wout(const float* __restrict__ wout,
                          _Float16* __restrict__ WL, _Float16* __restrict__ WR)
{
    const int idx = blockIdx.x * 256 + threadIdx.x;   // 512*512
    const int o = idx >> 9, j = idx & 511;
    WL[idx] = (_Float16)wout[o * 1024 + j];
    WR[idx] = (_Float16)wout[o * 1024 + 512 + j];
}

// only the 151 real rows; rows 151..255 stay poisoned (never read downstream)
__global__ void prep_wcls(const float* __restrict__ wcls, _Float16* __restrict__ w16)
{
    const int k = blockIdx.x * 256 + threadIdx.x;   // 77312
    const int d = blockIdx.y;                        // 0..150
    w16[(size_t)d * (C_ * H_) + k] = (_Float16)wcls[(size_t)d * (C_ * H_) + k];
}

__global__ void k_cast(const float* __restrict__ src, _Float16* __restrict__ dst, int n)
{
    const int i = blockIdx.x * 256 + threadIdx.x;
    if (i < n) dst[i] = (_Float16)src[i];
}

__global__ void prep_bias(const float* b3w, const float* b3u, const float* b4w,
                          const float* b4u, const float* b5w, const float* b5u,
                          float* bz, float* br, float* b5)
{
    const int i = threadIdx.x;   // 512 threads
    bz[i] = b3w[i] + b3u[i];
    br[i] = b4w[i] + b4u[i];
    b5[i] = b5w[i] + b5u[i];
}

__global__ void prep_hid(const float* __restrict__ input, float* __restrict__ hid)
{
    const int idx = blockIdx.x * 256 + threadIdx.x;   // NR*128
    const unsigned row = idx >> 7;
    const int h4 = (idx & 127) << 2;
    const unsigned n = row / 151u;
    f32x4 v = *(const f32x4*)&input[(size_t)n * H_ + h4];
    *(f32x4*)&hid[(size_t)row * H_ + h4] = v;
}

__global__ void k_reduce(const float* __restrict__ partial, const float* __restrict__ bcls,
                         float* __restrict__ out)
{
    const int idx = blockIdx.x * 256 + threadIdx.x;   // NR
    const unsigned n = (unsigned)idx / 151u;
    const unsigned d = (unsigned)idx - n * 151u;
    float s = 0.f;
    for (int z = 0; z < C_; ++z)
        s += partial[(size_t)z * (NOBJ * 256) + n * 256 + d];
    out[idx] = s + bcls[d];
}

// ---------------------------------------------------------------------------

extern "C" void kernel_launch(void* const* d_in, const int* in_sizes, int n_in,
                              void* d_out, int out_size, void* d_ws, size_t ws_size,
                              hipStream_t stream)
{
    const float* input  = (const float*)d_in[0];
    const float* matrix = (const float*)d_in[1];
    const float* w3w = (const float*)d_in[2];
    const float* b3w = (const float*)d_in[3];
    const float* w3u = (const float*)d_in[4];
    const float* b3u = (const float*)d_in[5];
    const float* w4w = (const float*)d_in[6];
    const float* b4w = (const float*)d_in[7];
    const float* w4u = (const float*)d_in[8];
    const float* b4u = (const float*)d_in[9];
    const float* w5w = (const float*)d_in[10];
    const float* b5w = (const float*)d_in[11];
    const float* w5u = (const float*)d_in[12];
    const float* b5u = (const float*)d_in[13];
    const float* wout = (const float*)d_in[14];
    const float* bout = (const float*)d_in[15];
    const float* wcls = (const float*)d_in[16];
    const float* bcls = (const float*)d_in[17];
    float* obj = (float*)d_out;

    char* ws = (char*)d_ws;
    size_t off = 0;
    auto take = [&](size_t bytes) -> char* {
        off = (off + 255) & ~(size_t)255;
        char* p = ws + off;
        off += bytes;
        return p;
    };

    _Float16* Wbig  = (_Float16*)take((size_t)1536 * KB * 2);     //  7.86 MB
    _Float16* MTh   = (_Float16*)take((size_t)KPAD * KPAD * 2);
    _Float16* MTl   = (_Float16*)take((size_t)KPAD * KPAD * 2);
    _Float16* Mrh   = (_Float16*)take((size_t)KPAD * KPAD * 2);
    _Float16* Mrl   = (_Float16*)take((size_t)KPAD * KPAD * 2);
    _Float16* W5u16 = (_Float16*)take((size_t)512 * 512 * 2);
    _Float16* WL16  = (_Float16*)take((size_t)512 * 512 * 2);
    _Float16* WR16  = (_Float16*)take((size_t)512 * 512 * 2);
    _Float16* in16  = (_Float16*)take((size_t)256 * 512 * 2);
    float*    bz    = (float*)take(512 * 4);
    float*    br    = (float*)take(512 * 4);
    float*    b5    = (float*)take(512 * 4);
    float*    Stmp  = (float*)take((size_t)8 * C_ * H_ * 4);      //  2.47 MB
    float*    S32   = (float*)take((size_t)C_ * H_ * 4);
    float*    base  = (float*)take((size_t)256 * 512 * 4);
    float*    hid32 = (float*)take((size_t)NR * H_ * 4);          // 79.17 MB
    _Float16* AVH   = (_Float16*)take((size_t)CHP * KA * 2);      // 49.81 MB
    _Float16* prec  = (_Float16*)take((size_t)CHP * 1536 * 2);    // 29.88 MB
    // time-based aliases:
    _Float16* p5u = AVH;                 // 2 split-K halves: 2*CHP*512*2 = 19.9 MB < AVH
    _Float16* OUT16 = AVH;               // epilogue out (after loop)
    _Float16* Wcls16 = (_Float16*)hid32; // hid dead after epilogue GEMM
    float* partial = (float*)((char*)hid32 + (size_t)NOBJ * C_ * H_ * 2);

    (void)in_sizes; (void)n_in; (void)out_size; (void)ws_size;

    // ---- prep ----
    prep_wbig<<<dim3((1536 * KB) / 256), 256, 0, stream>>>(w3w, w3u, w4w, w4u, w5w, w5u, Wbig);
    prep_m<<<dim3((KPAD * KPAD) / 256), 256, 0, stream>>>(matrix, MTh, MTl, Mrh, Mrl);
    k_cast<<<dim3((512 * 512) / 256), 256, 0, stream>>>(w5u, W5u16, 512 * 512);
    prep_wout<<<dim3((512 * 512) / 256), 256, 0, stream>>>(wout, WL16, WR16);
    k_cast<<<dim3((256 * 512) / 256), 256, 0, stream>>>(input, in16, 256 * 512);
    prep_bias<<<dim3(1), 512, 0, stream>>>(b3w, b3u, b4w, b4u, b5w, b5u, bz, br, b5);
    prep_hid<<<dim3((NR * 128) / 256), 256, 0, stream>>>(input, hid32);
    gemm_kernel<0, _Float16, false><<<dim3(2, 4, 1), 256, 0, stream>>>(
        in16, 512, WR16, 512, base, 512, nullptr, nullptr, 512, 0);

    // ---- 3 GGNN steps, 4 object-chunks each ----
    for (int t = 0; t < 3; ++t) {
        k_sreduce<<<dim3(C_, 8), 64, 0, stream>>>(hid32, Stmp);
        k_sfold<<<dim3((C_ * H_) / 256), 256, 0, stream>>>(Stmp, S32);
        for (int cc = 0; cc < 4; ++cc) {
            const int cbase = cc * CH;
            mix_kernel<<<dim3(NCH, 8), 256, 0, stream>>>(
                hid32, S32, MTh, MTl, Mrh, Mrl, AVH, cbase);
            // gate GEMM (virtual K=3584 over physical B 2560), 256x256 counted-vmcnt
            gemm256<<<dim3(CHP / 256, 1536 / 256, 1), 512, 0, stream>>>(
                AVH, Wbig, prec);
            k_ew1<<<dim3((CH * 128) / 256), 256, 0, stream>>>(prec, hid32, bz, br, cbase);
            // p5u = (r*h) @ W5u^T, split-K=2 (f16 partials summed in ew2)
            gemm_kernel<1, _Float16, false><<<dim3(CHP / 128, 4, 2), 256, 0, stream>>>(
                prec + 512, 1536, W5u16, 512, p5u, 512, nullptr, nullptr, 256, CHP * 512);
            k_ew2<<<dim3((CH * 128) / 256), 256, 0, stream>>>(
                prec, p5u, p5u + (size_t)CHP * 512, hid32, b5, cbase);
        }
    }

    // ---- epilogue: OUT = relu(hid @ WL^T + base[n] + bout)  (A is f32) ----
    gemm_kernel<2, float, false><<<dim3(NR / 128, 512 / 128, 1), 256, 0, stream>>>(
        hid32, 512, WL16, 512, OUT16, 512, bout, base, 512, 0);

    // ---- classifier: split-K over 151 chunks of 512 ----
    prep_wcls<<<dim3((C_ * H_) / 256, C_), 256, 0, stream>>>(wcls, Wcls16);
    gemm_kernel<0, _Float16, false><<<dim3(NOBJ / 128, 256 / 128, C_), 256, 0, stream>>>(
        OUT16, C_ * H_, Wcls16, C_ * H_, partial, 256, nullptr, nullptr, 512, NOBJ * 256);
    k_reduce<<<dim3(NR / 256), 256, 0, stream>>>(partial, bcls, obj);
}